// Round 11
// baseline (90.478 us; speedup 1.0000x reference)
//
#include <hip/hip_runtime.h>
#include <hip/hip_bf16.h>

// ---------- helpers ----------
typedef __attribute__((ext_vector_type(4))) float f32x4;
typedef __attribute__((ext_vector_type(8))) short s16x8;

#define MFMA16(a, b, c) __builtin_amdgcn_mfma_f32_16x16x32_bf16(a, b, c, 0, 0, 0)

__device__ __forceinline__ void gld_lds16(const void* g, void* l) {
  __builtin_amdgcn_global_load_lds(
      (const __attribute__((address_space(1))) unsigned int*)g,
      (__attribute__((address_space(3))) unsigned int*)l, 16, 0, 0);
}

__device__ __forceinline__ unsigned short f2bf(float f) {
  union { __hip_bfloat16 b; unsigned short u; } cv;
  cv.b = __float2bfloat16(f);
  return cv.u;
}
__device__ __forceinline__ float bf2f(unsigned short u) {
  union { unsigned short u; __hip_bfloat16 b; } cv;
  cv.u = u;
  return __bfloat162float(cv.b);
}

// ---------- kernel 1: W [K][N] f32 -> W^T [N][K] bf16 ----------
__global__ void transw(const float* W0, unsigned short* H0,
                       const float* W1, unsigned short* H1,
                       const float* W2, unsigned short* H2,
                       const float* W3, unsigned short* H3) {
  __shared__ float tile[64 * 65];
  const float* W; unsigned short* H;
  switch (blockIdx.y) {
    case 0: W = W0; H = H0; break;
    case 1: W = W1; H = H1; break;
    case 2: W = W2; H = H2; break;
    default: W = W3; H = H3; break;
  }
  const int t = threadIdx.x;
  const int tk0 = (blockIdx.x & 15) * 64;   // k tile
  const int tn0 = (blockIdx.x >> 4) * 64;   // n tile
  for (int i = 0; i < 16; ++i) {
    int idx = i * 256 + t;
    int r = idx >> 6, c = idx & 63;
    tile[r * 65 + c] = W[(size_t)(tk0 + r) * 1024 + tn0 + c];
  }
  __syncthreads();
  for (int i = 0; i < 16; ++i) {
    int idx = i * 256 + t;
    int r = idx >> 6, c = idx & 63;   // r: n offset, c: k offset
    H[(size_t)(tn0 + r) * 1024 + tk0 + c] = f2bf(tile[c * 65 + r]);
  }
}

// ---------- LDS layout (BK=64, bf16) ----------
// One matrix row = 64 shorts = one 128-B LDS row. Granule gno (8 shorts) of
// row r stored at slot gno^(r&7); gno -> k offset (gno>>2)*32 + (gno&3)*8.
// Read frag (row ar, k-group ks, lane gh): slot = ((ks<<2)|gh) ^ (ar&7).

// ---------- kernel 3a: QKV GEMM, 256x256 tile, 8 waves, BK=64, dbuf ----------
// A read DIRECTLY as f32 (fused convert): reg-staged (T14) global->reg->cvt->
// ds_write into the bf16 granule layout. B staged via global_load_lds.
// Counted vmcnt: (12) at step top retires B(t); (4) post-MFMA retires A-regs.
// g==0,1 (Q,K): out [b*16+h][s][64]. g==2 (V): out TRANSPOSED [b*16+h][d][2048 s].
struct QkvArgs {
  const float* A[3];            // f32 activations
  const unsigned short* B[3];   // bf16 W^T
  const float* bias[3];
  unsigned short* out[3];
};

__global__ __launch_bounds__(512, 2)
void gemm_qkv(QkvArgs args) {
  const int K = 1024;
  __shared__ __align__(16) unsigned short lds[65536];   // 128 KB: A 2x32KB | B 2x32KB
  const int tid = threadIdx.x;
  const int lane = tid & 63, w = tid >> 6;

  // XCD-aware bijective swizzle (192 % 8 == 0)
  const int nwg = 192;
  const int orig = blockIdx.x;
  const int swz = (orig & 7) * (nwg >> 3) + (orig >> 3);
  const int g = swz >> 6;          // 64 blocks per gemm (16 M x 4 N)
  const int tl = swz & 63;
  const int m0 = (tl >> 2) * 256, n0 = (tl & 3) * 256;

  const float* A = args.A[g];
  const unsigned short* B = args.B[g];
  const float* bias = args.bias[g];
  unsigned short* out = args.out[g];

  const int wm = (w >> 2) * 128, wn = (w & 3) * 64;   // wave tile 128x64
  const int fr = lane & 15, gh = lane >> 4;

  // ---- A reg-staging geometry: thread -> row ar_, k-half khalf (32 floats)
  const int ar_ = tid >> 1;
  const int p_ = tid & 1;
  const int khalf = p_ ^ ((ar_ >> 2) & 1);   // granule bit2 = khalf ^ bit2(ar_&7)... chosen so slots 4p..4p+3 map here
  const float* aSrc = A + (size_t)(m0 + ar_) * K + khalf * 32;

  // ---- B gld_lds geometry (4 sweeps)
  const unsigned short* bP[4]; int bDst[4];
  #pragma unroll
  for (int s = 0; s < 4; ++s) {
    const int G = s * 512 + tid;
    const int r = G >> 3, slot = G & 7;
    const int gno = slot ^ (r & 7);
    const int ko = (gno >> 2) * 32 + (gno & 3) * 8;
    bP[s] = B + (size_t)(n0 + r) * K + ko;
    bDst[s] = G * 8;
  }
  auto stageB = [&](int u, int kt) {
    #pragma unroll
    for (int s = 0; s < 4; ++s)
      gld_lds16(bP[s] + kt, &lds[32768 + u * 16384 + bDst[s]]);
  };

  float4 av[8];
  auto loadA = [&](int kt) {
    #pragma unroll
    for (int j = 0; j < 8; ++j)
      av[j] = *(const float4*)(aSrc + kt + j * 4);
  };
  // write granule j (floats j*8..j*8+7 = global granule gno = khalf*4+j) to
  // slot gno^(ar_&7) of LDS row ar_ in buffer u.
  auto writeA = [&](int u) {
    #pragma unroll
    for (int j = 0; j < 4; ++j) {
      const float4 lo = av[2 * j], hi = av[2 * j + 1];
      s16x8 v;
      v[0] = (short)f2bf(lo.x); v[1] = (short)f2bf(lo.y);
      v[2] = (short)f2bf(lo.z); v[3] = (short)f2bf(lo.w);
      v[4] = (short)f2bf(hi.x); v[5] = (short)f2bf(hi.y);
      v[6] = (short)f2bf(hi.z); v[7] = (short)f2bf(hi.w);
      const int slot = (khalf * 4 + j) ^ (ar_ & 7);
      *(s16x8*)&lds[u * 16384 + ar_ * 64 + slot * 8] = v;
    }
  };

  f32x4 acc[8][4] = {};

  // ---- prologue: stage K-tile 0
  loadA(0);
  stageB(0, 0);
  asm volatile("s_waitcnt vmcnt(4)" ::: "memory");   // A regs done (B's 4 pending)
  writeA(0);
  asm volatile("s_waitcnt vmcnt(0) lgkmcnt(0)" ::: "memory");
  __builtin_amdgcn_s_barrier();
  __builtin_amdgcn_sched_barrier(0);

  #pragma unroll 1
  for (int t = 0; t < 16; ++t) {
    const int u = t & 1;
    if (t < 15) {
      loadA((t + 1) * 64);                 // 8 VMEM -> regs
      stageB(u ^ 1, (t + 1) * 64);         // 4 VMEM -> LDS
      asm volatile("s_waitcnt vmcnt(12)" ::: "memory");   // retire B(t)
    } else {
      asm volatile("s_waitcnt vmcnt(0)" ::: "memory");
    }
    const unsigned short* La = &lds[u * 16384];
    const unsigned short* Lb = &lds[32768 + u * 16384];
    s16x8 b[2][4];
    #pragma unroll
    for (int ks = 0; ks < 2; ++ks)
      #pragma unroll
      for (int nt = 0; nt < 4; ++nt) {
        const int br = wn + nt * 16 + fr;
        b[ks][nt] = *(const s16x8*)&Lb[br * 64 + (((ks << 2) | gh) ^ (br & 7)) * 8];
      }
    #pragma unroll
    for (int q = 0; q < 4; ++q) {
      s16x8 a[2][2];
      #pragma unroll
      for (int i = 0; i < 2; ++i)
        #pragma unroll
        for (int ks = 0; ks < 2; ++ks) {
          const int ar = wm + (q * 2 + i) * 16 + fr;
          a[i][ks] = *(const s16x8*)&La[ar * 64 + (((ks << 2) | gh) ^ (ar & 7)) * 8];
        }
      #pragma unroll
      for (int i = 0; i < 2; ++i)
        #pragma unroll
        for (int nt = 0; nt < 4; ++nt) {
          acc[q * 2 + i][nt] = MFMA16(a[i][0], b[0][nt], acc[q * 2 + i][nt]);
          acc[q * 2 + i][nt] = MFMA16(a[i][1], b[1][nt], acc[q * 2 + i][nt]);
        }
    }
    if (t < 15) {
      asm volatile("s_waitcnt vmcnt(4)" ::: "memory");    // A(t+1) regs landed
      writeA(u ^ 1);
      asm volatile("s_waitcnt lgkmcnt(0)" ::: "memory");  // ds_writes visible
    }
    __builtin_amdgcn_sched_barrier(0);
    __builtin_amdgcn_s_barrier();
    __builtin_amdgcn_sched_barrier(0);
  }

  // ---- epilogue: acc -> LDS -> coalesced 16B stores
  float bv[4];
  #pragma unroll
  for (int nt = 0; nt < 4; ++nt) bv[nt] = bias[n0 + wn + nt * 16 + fr];
  unsigned short* eb = &lds[0];   // 65536 shorts = 256 x 256
  __syncthreads();
  if (g == 2) {
    // V: store C^T n-major with per-row XOR; s-major re-read is b128 conflict-free
    #pragma unroll
    for (int mt = 0; mt < 8; ++mt)
      #pragma unroll
      for (int nt = 0; nt < 4; ++nt) {
        const int nl = wn + nt * 16 + fr;
        f32x4 r = acc[mt][nt];
        #pragma unroll
        for (int j = 0; j < 4; ++j) {
          const int sl = wm + mt * 16 + gh * 4 + j;
          eb[nl * 256 + (sl ^ ((nl & 7) << 3))] = f2bf(r[j] + bv[nt]);
        }
      }
  } else {
    #pragma unroll
    for (int mt = 0; mt < 8; ++mt)
      #pragma unroll
      for (int nt = 0; nt < 4; ++nt) {
        const int nl = wn + nt * 16 + fr;
        f32x4 r = acc[mt][nt];
        #pragma unroll
        for (int j = 0; j < 4; ++j) {
          const int sl = wm + mt * 16 + gh * 4 + j;
          eb[sl * 256 + nl] = f2bf(r[j] + bv[nt]);
        }
      }
  }
  __syncthreads();
  const int b2 = m0 >> 11;
  if (g == 2) {
    // out[b*16+h][d][2048 s]: thread copies 8 shorts along s (b128 LDS read)
    #pragma unroll
    for (int it = 0; it < 16; ++it) {
      const int u = it * 512 + tid;
      const int nl = u >> 5, sc = u & 31;
      s16x8 v = *(const s16x8*)&eb[nl * 256 + ((sc * 8) ^ ((nl & 7) << 3))];
      const int gn = n0 + nl, h = gn >> 6, d = gn & 63;
      *(s16x8*)&out[((size_t)((b2 * 16 + h) * 64 + d)) * 2048 + (m0 & 2047) + sc * 8] = v;
    }
  } else {
    // out[b*16+h][s][64]: thread copies 8 shorts along d (16B store)
    #pragma unroll
    for (int it = 0; it < 16; ++it) {
      const int u = it * 512 + tid;
      const int sl = u >> 5, n8 = (u & 31) * 8;
      s16x8 v = *(const s16x8*)&eb[sl * 256 + n8];
      const int s = m0 + sl;
      const int gn = n0 + n8, h = gn >> 6, d = gn & 63;
      *(s16x8*)&out[(((size_t)(b2 * 16 + h)) * 2048 + (s & 2047)) * 64 + d] = v;
    }
  }
}

// ---------- kernel 3b: O-proj bf16 GEMM, 128x128 tile, 4 waves, BK=64, dbuf ----------
__global__ __launch_bounds__(256, 2)
void gemm_oproj(const unsigned short* __restrict__ A, const unsigned short* __restrict__ B,
                const float* __restrict__ bias, float* __restrict__ out) {
  const int K = 1024, N = 1024;
  __shared__ __align__(16) unsigned short lds[32768];   // 64 KB -> 2 blocks/CU
  const int tid = threadIdx.x;
  const int lane = tid & 63, wid = tid >> 6;

  const int nwg = 256;
  const int orig = blockIdx.x;
  const int swz = (orig & 7) * (nwg >> 3) + (orig >> 3);
  const int m0 = (swz >> 3) * 128, n0 = (swz & 7) * 128;

  const int wm = (wid >> 1) * 64, wn = (wid & 1) * 64;
  const int fr = lane & 15, gh = lane >> 4;

  const unsigned short* aP[4]; const unsigned short* bP[4]; int dstoff[4];
  #pragma unroll
  for (int s = 0; s < 4; ++s) {
    const int G = s * 256 + tid;
    const int r = G >> 3, slot = G & 7;
    const int gno = slot ^ (r & 7);
    const int ko = (gno >> 2) * 32 + (gno & 3) * 8;
    aP[s] = A + (size_t)(m0 + r) * K + ko;
    bP[s] = B + (size_t)(n0 + r) * K + ko;
    dstoff[s] = G * 8;
  }
  auto stageAll = [&](int u, int kt) {
    #pragma unroll
    for (int s = 0; s < 4; ++s) {
      gld_lds16(aP[s] + kt, &lds[u * 8192 + dstoff[s]]);
      gld_lds16(bP[s] + kt, &lds[16384 + u * 8192 + dstoff[s]]);
    }
  };

  f32x4 acc[4][4] = {};

  stageAll(0, 0);
  asm volatile("s_waitcnt vmcnt(0)" ::: "memory");
  __builtin_amdgcn_s_barrier();
  __builtin_amdgcn_sched_barrier(0);

  #pragma unroll 1
  for (int t = 0; t < 16; ++t) {
    const int u = t & 1;
    if (t < 15) stageAll(u ^ 1, (t + 1) * 64);
    const unsigned short* La = &lds[u * 8192];
    const unsigned short* Lb = &lds[16384 + u * 8192];
    s16x8 b[2][4];
    #pragma unroll
    for (int ks = 0; ks < 2; ++ks)
      #pragma unroll
      for (int nt = 0; nt < 4; ++nt) {
        const int br = wn + nt * 16 + fr;
        b[ks][nt] = *(const s16x8*)&Lb[br * 64 + (((ks << 2) | gh) ^ (br & 7)) * 8];
      }
    #pragma unroll
    for (int q = 0; q < 2; ++q) {
      s16x8 a[2][2];
      #pragma unroll
      for (int i = 0; i < 2; ++i)
        #pragma unroll
        for (int ks = 0; ks < 2; ++ks) {
          const int ar = wm + (q * 2 + i) * 16 + fr;
          a[i][ks] = *(const s16x8*)&La[ar * 64 + (((ks << 2) | gh) ^ (ar & 7)) * 8];
        }
      #pragma unroll
      for (int i = 0; i < 2; ++i)
        #pragma unroll
        for (int nt = 0; nt < 4; ++nt) {
          acc[q * 2 + i][nt] = MFMA16(a[i][0], b[0][nt], acc[q * 2 + i][nt]);
          acc[q * 2 + i][nt] = MFMA16(a[i][1], b[1][nt], acc[q * 2 + i][nt]);
        }
    }
    __builtin_amdgcn_sched_barrier(0);
    if (t < 15) { asm volatile("s_waitcnt vmcnt(0)" ::: "memory"); }
    __builtin_amdgcn_s_barrier();
    __builtin_amdgcn_sched_barrier(0);
  }

  #pragma unroll
  for (int mt = 0; mt < 4; ++mt) {
    const int gm = m0 + wm + mt * 16 + (gh << 2);
    #pragma unroll
    for (int nt = 0; nt < 4; ++nt) {
      const int gn = n0 + wn + nt * 16 + fr;
      const float bvv = bias[gn];
      f32x4 r = acc[mt][nt];
      #pragma unroll
      for (int j = 0; j < 4; ++j)
        out[(size_t)(gm + j) * N + gn] = r[j] + bvv;
    }
  }
}

// ---------- kernel 4: block-diagonal attention, MFMA core ----------
// grid 1024 = hb*32 + qb. Q,K: [hb][2048 s][64 d] bf16. Vt: [hb][64 d][2048 s] bf16.
// LDS tiles [64][64] bf16 with granule-XOR: granule g of row r stored at slot g^(r&7).
__global__ __launch_bounds__(256, 2)
void attn_mfma(const unsigned short* __restrict__ Q, const unsigned short* __restrict__ Kb,
               const unsigned short* __restrict__ Vt, unsigned short* __restrict__ X) {
  __shared__ __align__(16) unsigned short qs[4096];
  __shared__ __align__(16) unsigned short ks2[4096];
  __shared__ __align__(16) unsigned short vs[4096];
  __shared__ __align__(16) unsigned short ps[4096];
  const int tid = threadIdx.x, lane = tid & 63, w = tid >> 6;
  const int hb = blockIdx.x >> 5, qb = blockIdx.x & 31;
  const size_t qkbase = ((size_t)hb * 2048 + qb * 64) * 64;
  const size_t vbase = (size_t)hb * 64 * 2048 + qb * 64;

  // stage Q, K, V^T (8 KB each); inverse-swizzled global source, linear LDS dest
  #pragma unroll
  for (int i = 0; i < 2; ++i) {
    const int G = i * 256 + tid;
    const int row = G >> 3, slot = G & 7;
    const int sg = slot ^ (row & 7);
    gld_lds16(Q + qkbase + row * 64 + sg * 8, &qs[G * 8]);
    gld_lds16(Kb + qkbase + row * 64 + sg * 8, &ks2[G * 8]);
    gld_lds16(Vt + vbase + (size_t)row * 2048 + sg * 8, &vs[G * 8]);
  }
  asm volatile("s_waitcnt vmcnt(0)" ::: "memory");
  __syncthreads();

  const int fr = lane & 15, gh = lane >> 4;
  const int arow = w * 16 + fr;   // this wave's A rows (q)

  // ---- QK^T: S[16q][64k] per wave
  s16x8 aq[2], bk[2][4];
  #pragma unroll
  for (int ks = 0; ks < 2; ++ks) {
    aq[ks] = *(const s16x8*)&qs[arow * 64 + (((ks * 4 + gh) ^ (arow & 7)) << 3)];
    #pragma unroll
    for (int nt = 0; nt < 4; ++nt) {
      const int krow = nt * 16 + fr;
      bk[ks][nt] = *(const s16x8*)&ks2[krow * 64 + (((ks * 4 + gh) ^ (krow & 7)) << 3)];
    }
  }
  f32x4 s[4] = {};
  #pragma unroll
  for (int ks = 0; ks < 2; ++ks)
    #pragma unroll
    for (int nt = 0; nt < 4; ++nt)
      s[nt] = MFMA16(aq[ks], bk[ks][nt], s[nt]);

  // ---- softmax: D row q = gh*4+j, col k = nt*16+fr -> reduce over fr's 16 lanes
  #pragma unroll
  for (int j = 0; j < 4; ++j) {
    float t0 = s[0][j] * 0.125f, t1 = s[1][j] * 0.125f;
    float t2 = s[2][j] * 0.125f, t3 = s[3][j] * 0.125f;
    float m = fmaxf(fmaxf(t0, t1), fmaxf(t2, t3));
    m = fmaxf(m, __shfl_xor(m, 1, 64));
    m = fmaxf(m, __shfl_xor(m, 2, 64));
    m = fmaxf(m, __shfl_xor(m, 4, 64));
    m = fmaxf(m, __shfl_xor(m, 8, 64));
    t0 = __expf(t0 - m); t1 = __expf(t1 - m);
    t2 = __expf(t2 - m); t3 = __expf(t3 - m);
    float sum = t0 + t1 + t2 + t3;
    sum += __shfl_xor(sum, 1, 64);
    sum += __shfl_xor(sum, 2, 64);
    sum += __shfl_xor(sum, 4, 64);
    sum += __shfl_xor(sum, 8, 64);
    const float r = 1.0f / sum;
    s[0][j] = t0 * r; s[1][j] = t1 * r; s[2][j] = t2 * r; s[3][j] = t3 * r;
  }

  // ---- P -> bf16 LDS (swizzled); wave writes/reads only its own 16 rows
  #pragma unroll
  for (int j = 0; j < 4; ++j) {
    const int q = w * 16 + gh * 4 + j;
    #pragma unroll
    for (int nt = 0; nt < 4; ++nt) {
      const int k = nt * 16 + fr;
      ps[q * 64 + (((k >> 3) ^ (q & 7)) << 3) + (k & 7)] = f2bf(s[nt][j]);
    }
  }

  // ---- PV: X[16q][64d] = P rows x V^T rows
  s16x8 ap[2], bv2[2][4];
  #pragma unroll
  for (int ks = 0; ks < 2; ++ks) {
    ap[ks] = *(const s16x8*)&ps[arow * 64 + (((ks * 4 + gh) ^ (arow & 7)) << 3)];
    #pragma unroll
    for (int nt = 0; nt < 4; ++nt) {
      const int drow = nt * 16 + fr;
      bv2[ks][nt] = *(const s16x8*)&vs[drow * 64 + (((ks * 4 + gh) ^ (drow & 7)) << 3)];
    }
  }
  f32x4 x[4] = {};
  #pragma unroll
  for (int ks = 0; ks < 2; ++ks)
    #pragma unroll
    for (int nt = 0; nt < 4; ++nt)
      x[nt] = MFMA16(ap[ks], bv2[ks][nt], x[nt]);

  // ---- write X: [b*2048 + s][h*64 + d] bf16
  const int b = hb >> 4, h = hb & 15;
  #pragma unroll
  for (int nt = 0; nt < 4; ++nt)
    #pragma unroll
    for (int j = 0; j < 4; ++j) {
      const int sgl = qb * 64 + w * 16 + gh * 4 + j;
      X[((size_t)(b * 2048 + sgl)) * 1024 + h * 64 + nt * 16 + fr] = f2bf(x[nt][j]);
    }
}

// ---------- launch ----------
extern "C" void kernel_launch(void* const* d_in, const int* in_sizes, int n_in,
                              void* d_out, int out_size, void* d_ws, size_t ws_size,
                              hipStream_t stream) {
  const float* query = (const float*)d_in[0];
  const float* key   = (const float*)d_in[1];
  const float* value = (const float*)d_in[2];
  const float* Wq = (const float*)d_in[3]; const float* bq = (const float*)d_in[4];
  const float* Wk = (const float*)d_in[5]; const float* bk = (const float*)d_in[6];
  const float* Wv = (const float*)d_in[7]; const float* bv = (const float*)d_in[8];
  const float* Wo = (const float*)d_in[9]; const float* bo = (const float*)d_in[10];
  float* out = (float*)d_out;

  const size_t W_E = 1024 * 1024;
  const size_t X_E = 4096 * 1024;
  unsigned char* p = (unsigned char*)d_ws;
  auto take = [&](size_t bytes) { void* r = (void*)p; p += bytes; return r; };

  unsigned short* wtq = (unsigned short*)take(W_E * 2);
  unsigned short* wtk = (unsigned short*)take(W_E * 2);
  unsigned short* wtv = (unsigned short*)take(W_E * 2);
  unsigned short* wto = (unsigned short*)take(W_E * 2);
  unsigned short* Qb = (unsigned short*)take(X_E * 2);
  unsigned short* Kb = (unsigned short*)take(X_E * 2);
  unsigned short* Vt = (unsigned short*)take(X_E * 2);
  unsigned short* ao = (unsigned short*)take(X_E * 2);
  (void)ws_size; (void)in_sizes; (void)n_in; (void)out_size;

  transw<<<dim3(256, 4), 256, 0, stream>>>(Wq, wtq, Wk, wtk, Wv, wtv, Wo, wto);

  QkvArgs qkv = {};
  qkv.A[0] = query; qkv.B[0] = wtq; qkv.bias[0] = bq; qkv.out[0] = Qb;
  qkv.A[1] = key;   qkv.B[1] = wtk; qkv.bias[1] = bk; qkv.out[1] = Kb;
  qkv.A[2] = value; qkv.B[2] = wtv; qkv.bias[2] = bv; qkv.out[2] = Vt;
  gemm_qkv<<<dim3(192), 512, 0, stream>>>(qkv);

  attn_mfma<<<dim3(1024), 256, 0, stream>>>(Qb, Kb, Vt, ao);

  gemm_oproj<<<dim3(256), 256, 0, stream>>>(ao, wto, bo, out);
}

// Round 12
// 80.952 us; speedup vs baseline: 1.1177x; 1.1177x over previous
//
#include <hip/hip_runtime.h>
#include <hip/hip_bf16.h>

// ---------- helpers ----------
typedef __attribute__((ext_vector_type(4))) float f32x4;
typedef __attribute__((ext_vector_type(8))) short s16x8;

#define MFMA16(a, b, c) __builtin_amdgcn_mfma_f32_16x16x32_bf16(a, b, c, 0, 0, 0)

__device__ __forceinline__ void gld_lds16(const void* g, void* l) {
  __builtin_amdgcn_global_load_lds(
      (const __attribute__((address_space(1))) unsigned int*)g,
      (__attribute__((address_space(3))) unsigned int*)l, 16, 0, 0);
}

__device__ __forceinline__ unsigned short f2bf(float f) {
  union { __hip_bfloat16 b; unsigned short u; } cv;
  cv.b = __float2bfloat16(f);
  return cv.u;
}
__device__ __forceinline__ float bf2f(unsigned short u) {
  union { unsigned short u; __hip_bfloat16 b; } cv;
  cv.u = u;
  return __bfloat162float(cv.b);
}

// ---------- kernel 1: W [K][N] f32 -> W^T [N][K] bf16 ----------
__global__ void transw(const float* W0, unsigned short* H0,
                       const float* W1, unsigned short* H1,
                       const float* W2, unsigned short* H2,
                       const float* W3, unsigned short* H3) {
  __shared__ float tile[64 * 65];
  const float* W; unsigned short* H;
  switch (blockIdx.y) {
    case 0: W = W0; H = H0; break;
    case 1: W = W1; H = H1; break;
    case 2: W = W2; H = H2; break;
    default: W = W3; H = H3; break;
  }
  const int t = threadIdx.x;
  const int tk0 = (blockIdx.x & 15) * 64;   // k tile
  const int tn0 = (blockIdx.x >> 4) * 64;   // n tile
  for (int i = 0; i < 16; ++i) {
    int idx = i * 256 + t;
    int r = idx >> 6, c = idx & 63;
    tile[r * 65 + c] = W[(size_t)(tk0 + r) * 1024 + tn0 + c];
  }
  __syncthreads();
  for (int i = 0; i < 16; ++i) {
    int idx = i * 256 + t;
    int r = idx >> 6, c = idx & 63;   // r: n offset, c: k offset
    H[(size_t)(tn0 + r) * 1024 + tk0 + c] = f2bf(tile[c * 65 + r]);
  }
}

// ---------- kernel 2: X [4096][1024] f32 -> bf16 ----------
__global__ void convert_x3(const float* A0, unsigned short* H0,
                           const float* A1, unsigned short* H1,
                           const float* A2, unsigned short* H2) {
  const float* src; unsigned short* h;
  switch (blockIdx.y) {
    case 0: src = A0; h = H0; break;
    case 1: src = A1; h = H1; break;
    default: src = A2; h = H2; break;
  }
  int i = blockIdx.x * 256 + threadIdx.x;   // float4 index
  float4 v = ((const float4*)src)[i];
  ((ushort4*)h)[i] = make_ushort4(f2bf(v.x), f2bf(v.y), f2bf(v.z), f2bf(v.w));
}

// ---------- LDS layout (BK=64, bf16) ----------
// One matrix row = 64 shorts = one 128-B LDS row. Granule gno (8 shorts) of
// row r stored at slot gno^(r&7); gno -> k offset (gno>>2)*32 + (gno&3)*8.
// Read frag (row ar, k-group ks, lane gh): slot = ((ks<<2)|gh) ^ (ar&7).

// ---------- kernel 3a: QKV bf16 GEMM, 256x256, 8 waves, BK=64, 4-phase ----------
// m201-style phase schedule. Per K-tile t (buf u=t&1), 4 phases, each:
// {ds_read phase subtile ; issue 2 stage loads (t+1 -> buf u^1) ; barrier ;
//  lgkmcnt(0) ; setprio(1) ; 16 MFMA ; setprio(0) ; [vmcnt gate] ; barrier}.
// Stage order: ph0->Bgrp0, ph1->Bgrp1, ph2->Aunits01, ph3->Aunits23.
// Gates: end-of-ph3 vmcnt(2) (leaves next tile's A23 in flight; B+A01 landed
// for next ph0/ph1); end-of-ph1 vmcnt(4) (retires this tile's A23 for ph2/3).
// Never drains to 0 mid-loop. g==0,1 (Q,K): out [b*16+h][s][64].
// g==2 (V): out TRANSPOSED [b*16+h][d][2048 s].
struct QkvArgs {
  const unsigned short* A[3];
  const unsigned short* B[3];
  const float* bias[3];
  unsigned short* out[3];
};

__global__ __launch_bounds__(512, 2)
void gemm_qkv(QkvArgs args) {
  const int K = 1024;
  __shared__ __align__(16) unsigned short lds[65536];   // A 2x32KB | B 2x32KB
  const int tid = threadIdx.x;
  const int lane = tid & 63, w = tid >> 6;

  // XCD-aware bijective swizzle (192 % 8 == 0)
  const int nwg = 192;
  const int orig = blockIdx.x;
  const int swz = (orig & 7) * (nwg >> 3) + (orig >> 3);
  const int g = swz >> 6;          // 64 blocks per gemm (16 M x 4 N)
  const int tl = swz & 63;
  const int m0 = (tl >> 2) * 256, n0 = (tl & 3) * 256;

  const unsigned short* A = args.A[g];
  const unsigned short* B = args.B[g];
  const float* bias = args.bias[g];
  unsigned short* out = args.out[g];

  const int wm = (w >> 2) * 128, wn = (w & 3) * 64;   // wave tile 128x64
  const int fr = lane & 15, gh = lane >> 4;

  // B stage groups g2 in {0,1}: rows [128*g2, 128*g2+128), 2 loads/thread
  const unsigned short* bSrc[2][2]; int bDst[2][2];
  #pragma unroll
  for (int g2 = 0; g2 < 2; ++g2)
    #pragma unroll
    for (int i = 0; i < 2; ++i) {
      const int G = i * 512 + tid;
      const int lr = G >> 3, slot = G & 7;
      const int r = g2 * 128 + lr;
      const int gno = slot ^ (r & 7);
      const int ko = (gno >> 2) * 32 + (gno & 3) * 8;
      bSrc[g2][i] = B + (size_t)(n0 + r) * K + ko;
      bDst[g2][i] = r * 64 + slot * 8;
    }
  // A units p in {0..3}: rows with ((r>>5)&3)==p (phase p's rows for both
  // wm groups), 1 load/thread each
  const unsigned short* aSrc[4]; int aDst[4];
  #pragma unroll
  for (int p = 0; p < 4; ++p) {
    const int lr = tid >> 3, slot = tid & 7;       // lr 0..63
    const int r = ((lr >> 5) << 7) + p * 32 + (lr & 31);
    const int gno = slot ^ (r & 7);
    const int ko = (gno >> 2) * 32 + (gno & 3) * 8;
    aSrc[p] = A + (size_t)(m0 + r) * K + ko;
    aDst[p] = r * 64 + slot * 8;
  }

  auto stageB = [&](int u, int g2, int kt) {
    gld_lds16(bSrc[g2][0] + kt, &lds[32768 + u * 16384 + bDst[g2][0]]);
    gld_lds16(bSrc[g2][1] + kt, &lds[32768 + u * 16384 + bDst[g2][1]]);
  };
  auto stageA2 = [&](int u, int pp, int kt) {     // units pp, pp+1
    gld_lds16(aSrc[pp] + kt, &lds[u * 16384 + aDst[pp]]);
    gld_lds16(aSrc[pp + 1] + kt, &lds[u * 16384 + aDst[pp + 1]]);
  };

  f32x4 acc[8][4] = {};

  // prologue: tile 0 into buf 0, order Bg0,Bg1,A01,A23; gate all but A23
  stageB(0, 0, 0); stageB(0, 1, 0); stageA2(0, 0, 0); stageA2(0, 2, 0);
  asm volatile("s_waitcnt vmcnt(2)" ::: "memory");
  __builtin_amdgcn_s_barrier();
  __builtin_amdgcn_sched_barrier(0);

  #pragma unroll 1
  for (int t = 0; t < 16; ++t) {
    const int u = t & 1;
    const unsigned short* La = &lds[u * 16384];
    const unsigned short* Lb = &lds[32768 + u * 16384];
    const int nkt = (t + 1) * 64;
    s16x8 breg[2][4];
    s16x8 a[2][2];

    // ---- phase 0: read all B frags (held in regs for the tile) + A q0
    #pragma unroll
    for (int ks = 0; ks < 2; ++ks)
      #pragma unroll
      for (int nt = 0; nt < 4; ++nt) {
        const int br = wn + nt * 16 + fr;
        breg[ks][nt] = *(const s16x8*)&Lb[br * 64 + (((ks << 2) | gh) ^ (br & 7)) * 8];
      }
    #pragma unroll
    for (int i = 0; i < 2; ++i)
      #pragma unroll
      for (int ks = 0; ks < 2; ++ks) {
        const int ar = wm + i * 16 + fr;
        a[i][ks] = *(const s16x8*)&La[ar * 64 + (((ks << 2) | gh) ^ (ar & 7)) * 8];
      }
    if (t < 15) stageB(u ^ 1, 0, nkt);
    __builtin_amdgcn_s_barrier();
    asm volatile("s_waitcnt lgkmcnt(0)" ::: "memory");
    __builtin_amdgcn_sched_barrier(0);
    __builtin_amdgcn_s_setprio(1);
    #pragma unroll
    for (int i = 0; i < 2; ++i)
      #pragma unroll
      for (int nt = 0; nt < 4; ++nt) {
        acc[i][nt] = MFMA16(a[i][0], breg[0][nt], acc[i][nt]);
        acc[i][nt] = MFMA16(a[i][1], breg[1][nt], acc[i][nt]);
      }
    __builtin_amdgcn_s_setprio(0);
    __builtin_amdgcn_s_barrier();

    // ---- phase 1: A q1; stage Bg1; gate A23(t) before ph2
    #pragma unroll
    for (int i = 0; i < 2; ++i)
      #pragma unroll
      for (int ks = 0; ks < 2; ++ks) {
        const int ar = wm + 32 + i * 16 + fr;
        a[i][ks] = *(const s16x8*)&La[ar * 64 + (((ks << 2) | gh) ^ (ar & 7)) * 8];
      }
    if (t < 15) stageB(u ^ 1, 1, nkt);
    __builtin_amdgcn_s_barrier();
    asm volatile("s_waitcnt lgkmcnt(0)" ::: "memory");
    __builtin_amdgcn_sched_barrier(0);
    __builtin_amdgcn_s_setprio(1);
    #pragma unroll
    for (int i = 0; i < 2; ++i)
      #pragma unroll
      for (int nt = 0; nt < 4; ++nt) {
        acc[2 + i][nt] = MFMA16(a[i][0], breg[0][nt], acc[2 + i][nt]);
        acc[2 + i][nt] = MFMA16(a[i][1], breg[1][nt], acc[2 + i][nt]);
      }
    __builtin_amdgcn_s_setprio(0);
    if (t < 15) { asm volatile("s_waitcnt vmcnt(4)" ::: "memory"); }
    else        { asm volatile("s_waitcnt vmcnt(0)" ::: "memory"); }
    __builtin_amdgcn_s_barrier();

    // ---- phase 2: A q2; stage A units 0,1
    #pragma unroll
    for (int i = 0; i < 2; ++i)
      #pragma unroll
      for (int ks = 0; ks < 2; ++ks) {
        const int ar = wm + 64 + i * 16 + fr;
        a[i][ks] = *(const s16x8*)&La[ar * 64 + (((ks << 2) | gh) ^ (ar & 7)) * 8];
      }
    if (t < 15) stageA2(u ^ 1, 0, nkt);
    __builtin_amdgcn_s_barrier();
    asm volatile("s_waitcnt lgkmcnt(0)" ::: "memory");
    __builtin_amdgcn_sched_barrier(0);
    __builtin_amdgcn_s_setprio(1);
    #pragma unroll
    for (int i = 0; i < 2; ++i)
      #pragma unroll
      for (int nt = 0; nt < 4; ++nt) {
        acc[4 + i][nt] = MFMA16(a[i][0], breg[0][nt], acc[4 + i][nt]);
        acc[4 + i][nt] = MFMA16(a[i][1], breg[1][nt], acc[4 + i][nt]);
      }
    __builtin_amdgcn_s_setprio(0);
    __builtin_amdgcn_s_barrier();

    // ---- phase 3: A q3; stage A units 2,3; gate next tile's ph0
    #pragma unroll
    for (int i = 0; i < 2; ++i)
      #pragma unroll
      for (int ks = 0; ks < 2; ++ks) {
        const int ar = wm + 96 + i * 16 + fr;
        a[i][ks] = *(const s16x8*)&La[ar * 64 + (((ks << 2) | gh) ^ (ar & 7)) * 8];
      }
    if (t < 15) stageA2(u ^ 1, 2, nkt);
    __builtin_amdgcn_s_barrier();
    asm volatile("s_waitcnt lgkmcnt(0)" ::: "memory");
    __builtin_amdgcn_sched_barrier(0);
    __builtin_amdgcn_s_setprio(1);
    #pragma unroll
    for (int i = 0; i < 2; ++i)
      #pragma unroll
      for (int nt = 0; nt < 4; ++nt) {
        acc[6 + i][nt] = MFMA16(a[i][0], breg[0][nt], acc[6 + i][nt]);
        acc[6 + i][nt] = MFMA16(a[i][1], breg[1][nt], acc[6 + i][nt]);
      }
    __builtin_amdgcn_s_setprio(0);
    asm volatile("s_waitcnt vmcnt(2)" ::: "memory");
    __builtin_amdgcn_s_barrier();
    __builtin_amdgcn_sched_barrier(0);
  }

  // ---- epilogue: acc -> LDS -> coalesced 16B stores
  float bv[4];
  #pragma unroll
  for (int nt = 0; nt < 4; ++nt) bv[nt] = bias[n0 + wn + nt * 16 + fr];
  unsigned short* eb = &lds[0];   // 65536 shorts = 256 x 256
  __syncthreads();
  if (g == 2) {
    // V: store C^T n-major with per-row XOR; s-major re-read is b128 conflict-free
    #pragma unroll
    for (int mt = 0; mt < 8; ++mt)
      #pragma unroll
      for (int nt = 0; nt < 4; ++nt) {
        const int nl = wn + nt * 16 + fr;
        f32x4 r = acc[mt][nt];
        #pragma unroll
        for (int j = 0; j < 4; ++j) {
          const int sl = wm + mt * 16 + gh * 4 + j;
          eb[nl * 256 + (sl ^ ((nl & 7) << 3))] = f2bf(r[j] + bv[nt]);
        }
      }
  } else {
    #pragma unroll
    for (int mt = 0; mt < 8; ++mt)
      #pragma unroll
      for (int nt = 0; nt < 4; ++nt) {
        const int nl = wn + nt * 16 + fr;
        f32x4 r = acc[mt][nt];
        #pragma unroll
        for (int j = 0; j < 4; ++j) {
          const int sl = wm + mt * 16 + gh * 4 + j;
          eb[sl * 256 + nl] = f2bf(r[j] + bv[nt]);
        }
      }
  }
  __syncthreads();
  const int b2 = m0 >> 11;
  if (g == 2) {
    // out[b*16+h][d][2048 s]: thread copies 8 shorts along s (b128 LDS read)
    #pragma unroll
    for (int it = 0; it < 16; ++it) {
      const int u = it * 512 + tid;
      const int nl = u >> 5, sc = u & 31;
      s16x8 v = *(const s16x8*)&eb[nl * 256 + ((sc * 8) ^ ((nl & 7) << 3))];
      const int gn = n0 + nl, h = gn >> 6, d = gn & 63;
      *(s16x8*)&out[((size_t)((b2 * 16 + h) * 64 + d)) * 2048 + (m0 & 2047) + sc * 8] = v;
    }
  } else {
    // out[b*16+h][s][64]: thread copies 8 shorts along d (16B store)
    #pragma unroll
    for (int it = 0; it < 16; ++it) {
      const int u = it * 512 + tid;
      const int sl = u >> 5, n8 = (u & 31) * 8;
      s16x8 v = *(const s16x8*)&eb[sl * 256 + n8];
      const int s = m0 + sl;
      const int gn = n0 + n8, h = gn >> 6, d = gn & 63;
      *(s16x8*)&out[(((size_t)(b2 * 16 + h)) * 2048 + (s & 2047)) * 64 + d] = v;
    }
  }
}

// ---------- kernel 3b: O-proj bf16 GEMM, 128x128 tile, 4 waves, BK=64, dbuf ----------
__global__ __launch_bounds__(256, 2)
void gemm_oproj(const unsigned short* __restrict__ A, const unsigned short* __restrict__ B,
                const float* __restrict__ bias, float* __restrict__ out) {
  const int K = 1024, N = 1024;
  __shared__ __align__(16) unsigned short lds[32768];   // 64 KB -> 2 blocks/CU
  const int tid = threadIdx.x;
  const int lane = tid & 63, wid = tid >> 6;

  const int nwg = 256;
  const int orig = blockIdx.x;
  const int swz = (orig & 7) * (nwg >> 3) + (orig >> 3);
  const int m0 = (swz >> 3) * 128, n0 = (swz & 7) * 128;

  const int wm = (wid >> 1) * 64, wn = (wid & 1) * 64;
  const int fr = lane & 15, gh = lane >> 4;

  const unsigned short* aP[4]; const unsigned short* bP[4]; int dstoff[4];
  #pragma unroll
  for (int s = 0; s < 4; ++s) {
    const int G = s * 256 + tid;
    const int r = G >> 3, slot = G & 7;
    const int gno = slot ^ (r & 7);
    const int ko = (gno >> 2) * 32 + (gno & 3) * 8;
    aP[s] = A + (size_t)(m0 + r) * K + ko;
    bP[s] = B + (size_t)(n0 + r) * K + ko;
    dstoff[s] = G * 8;
  }
  auto stageAll = [&](int u, int kt) {
    #pragma unroll
    for (int s = 0; s < 4; ++s) {
      gld_lds16(aP[s] + kt, &lds[u * 8192 + dstoff[s]]);
      gld_lds16(bP[s] + kt, &lds[16384 + u * 8192 + dstoff[s]]);
    }
  };

  f32x4 acc[4][4] = {};

  stageAll(0, 0);
  asm volatile("s_waitcnt vmcnt(0)" ::: "memory");
  __builtin_amdgcn_s_barrier();
  __builtin_amdgcn_sched_barrier(0);

  #pragma unroll 1
  for (int t = 0; t < 16; ++t) {
    const int u = t & 1;
    if (t < 15) stageAll(u ^ 1, (t + 1) * 64);
    const unsigned short* La = &lds[u * 8192];
    const unsigned short* Lb = &lds[16384 + u * 8192];
    s16x8 b[2][4];
    #pragma unroll
    for (int ks = 0; ks < 2; ++ks)
      #pragma unroll
      for (int nt = 0; nt < 4; ++nt) {
        const int br = wn + nt * 16 + fr;
        b[ks][nt] = *(const s16x8*)&Lb[br * 64 + (((ks << 2) | gh) ^ (br & 7)) * 8];
      }
    #pragma unroll
    for (int q = 0; q < 2; ++q) {
      s16x8 a[2][2];
      #pragma unroll
      for (int i = 0; i < 2; ++i)
        #pragma unroll
        for (int ks = 0; ks < 2; ++ks) {
          const int ar = wm + (q * 2 + i) * 16 + fr;
          a[i][ks] = *(const s16x8*)&La[ar * 64 + (((ks << 2) | gh) ^ (ar & 7)) * 8];
        }
      #pragma unroll
      for (int i = 0; i < 2; ++i)
        #pragma unroll
        for (int nt = 0; nt < 4; ++nt) {
          acc[q * 2 + i][nt] = MFMA16(a[i][0], b[0][nt], acc[q * 2 + i][nt]);
          acc[q * 2 + i][nt] = MFMA16(a[i][1], b[1][nt], acc[q * 2 + i][nt]);
        }
    }
    __builtin_amdgcn_sched_barrier(0);
    if (t < 15) { asm volatile("s_waitcnt vmcnt(0)" ::: "memory"); }
    __builtin_amdgcn_s_barrier();
    __builtin_amdgcn_sched_barrier(0);
  }

  #pragma unroll
  for (int mt = 0; mt < 4; ++mt) {
    const int gm = m0 + wm + mt * 16 + (gh << 2);
    #pragma unroll
    for (int nt = 0; nt < 4; ++nt) {
      const int gn = n0 + wn + nt * 16 + fr;
      const float bvv = bias[gn];
      f32x4 r = acc[mt][nt];
      #pragma unroll
      for (int j = 0; j < 4; ++j)
        out[(size_t)(gm + j) * N + gn] = r[j] + bvv;
    }
  }
}

// ---------- kernel 4: block-diagonal attention, MFMA core ----------
// grid 1024 = hb*32 + qb. Q,K: [hb][2048 s][64 d] bf16. Vt: [hb][64 d][2048 s] bf16.
// LDS tiles [64][64] bf16 with granule-XOR: granule g of row r stored at slot g^(r&7).
__global__ __launch_bounds__(256, 2)
void attn_mfma(const unsigned short* __restrict__ Q, const unsigned short* __restrict__ Kb,
               const unsigned short* __restrict__ Vt, unsigned short* __restrict__ X) {
  __shared__ __align__(16) unsigned short qs[4096];
  __shared__ __align__(16) unsigned short ks2[4096];
  __shared__ __align__(16) unsigned short vs[4096];
  __shared__ __align__(16) unsigned short ps[4096];
  const int tid = threadIdx.x, lane = tid & 63, w = tid >> 6;
  const int hb = blockIdx.x >> 5, qb = blockIdx.x & 31;
  const size_t qkbase = ((size_t)hb * 2048 + qb * 64) * 64;
  const size_t vbase = (size_t)hb * 64 * 2048 + qb * 64;

  #pragma unroll
  for (int i = 0; i < 2; ++i) {
    const int G = i * 256 + tid;
    const int row = G >> 3, slot = G & 7;
    const int sg = slot ^ (row & 7);
    gld_lds16(Q + qkbase + row * 64 + sg * 8, &qs[G * 8]);
    gld_lds16(Kb + qkbase + row * 64 + sg * 8, &ks2[G * 8]);
    gld_lds16(Vt + vbase + (size_t)row * 2048 + sg * 8, &vs[G * 8]);
  }
  asm volatile("s_waitcnt vmcnt(0)" ::: "memory");
  __syncthreads();

  const int fr = lane & 15, gh = lane >> 4;
  const int arow = w * 16 + fr;

  s16x8 aq[2], bk[2][4];
  #pragma unroll
  for (int ks = 0; ks < 2; ++ks) {
    aq[ks] = *(const s16x8*)&qs[arow * 64 + (((ks * 4 + gh) ^ (arow & 7)) << 3)];
    #pragma unroll
    for (int nt = 0; nt < 4; ++nt) {
      const int krow = nt * 16 + fr;
      bk[ks][nt] = *(const s16x8*)&ks2[krow * 64 + (((ks * 4 + gh) ^ (krow & 7)) << 3)];
    }
  }
  f32x4 s[4] = {};
  #pragma unroll
  for (int ks = 0; ks < 2; ++ks)
    #pragma unroll
    for (int nt = 0; nt < 4; ++nt)
      s[nt] = MFMA16(aq[ks], bk[ks][nt], s[nt]);

  #pragma unroll
  for (int j = 0; j < 4; ++j) {
    float t0 = s[0][j] * 0.125f, t1 = s[1][j] * 0.125f;
    float t2 = s[2][j] * 0.125f, t3 = s[3][j] * 0.125f;
    float m = fmaxf(fmaxf(t0, t1), fmaxf(t2, t3));
    m = fmaxf(m, __shfl_xor(m, 1, 64));
    m = fmaxf(m, __shfl_xor(m, 2, 64));
    m = fmaxf(m, __shfl_xor(m, 4, 64));
    m = fmaxf(m, __shfl_xor(m, 8, 64));
    t0 = __expf(t0 - m); t1 = __expf(t1 - m);
    t2 = __expf(t2 - m); t3 = __expf(t3 - m);
    float sum = t0 + t1 + t2 + t3;
    sum += __shfl_xor(sum, 1, 64);
    sum += __shfl_xor(sum, 2, 64);
    sum += __shfl_xor(sum, 4, 64);
    sum += __shfl_xor(sum, 8, 64);
    const float r = 1.0f / sum;
    s[0][j] = t0 * r; s[1][j] = t1 * r; s[2][j] = t2 * r; s[3][j] = t3 * r;
  }

  #pragma unroll
  for (int j = 0; j < 4; ++j) {
    const int q = w * 16 + gh * 4 + j;
    #pragma unroll
    for (int nt = 0; nt < 4; ++nt) {
      const int k = nt * 16 + fr;
      ps[q * 64 + (((k >> 3) ^ (q & 7)) << 3) + (k & 7)] = f2bf(s[nt][j]);
    }
  }

  s16x8 ap[2], bv2[2][4];
  #pragma unroll
  for (int ks = 0; ks < 2; ++ks) {
    ap[ks] = *(const s16x8*)&ps[arow * 64 + (((ks * 4 + gh) ^ (arow & 7)) << 3)];
    #pragma unroll
    for (int nt = 0; nt < 4; ++nt) {
      const int drow = nt * 16 + fr;
      bv2[ks][nt] = *(const s16x8*)&vs[drow * 64 + (((ks * 4 + gh) ^ (drow & 7)) << 3)];
    }
  }
  f32x4 x[4] = {};
  #pragma unroll
  for (int ks = 0; ks < 2; ++ks)
    #pragma unroll
    for (int nt = 0; nt < 4; ++nt)
      x[nt] = MFMA16(ap[ks], bv2[ks][nt], x[nt]);

  const int b = hb >> 4, h = hb & 15;
  #pragma unroll
  for (int nt = 0; nt < 4; ++nt)
    #pragma unroll
    for (int j = 0; j < 4; ++j) {
      const int sgl = qb * 64 + w * 16 + gh * 4 + j;
      X[((size_t)(b * 2048 + sgl)) * 1024 + h * 64 + nt * 16 + fr] = f2bf(x[nt][j]);
    }
}

// ---------- launch ----------
extern "C" void kernel_launch(void* const* d_in, const int* in_sizes, int n_in,
                              void* d_out, int out_size, void* d_ws, size_t ws_size,
                              hipStream_t stream) {
  const float* query = (const float*)d_in[0];
  const float* key   = (const float*)d_in[1];
  const float* value = (const float*)d_in[2];
  const float* Wq = (const float*)d_in[3]; const float* bq = (const float*)d_in[4];
  const float* Wk = (const float*)d_in[5]; const float* bk = (const float*)d_in[6];
  const float* Wv = (const float*)d_in[7]; const float* bv = (const float*)d_in[8];
  const float* Wo = (const float*)d_in[9]; const float* bo = (const float*)d_in[10];
  float* out = (float*)d_out;

  const size_t W_E = 1024 * 1024;
  const size_t X_E = 4096 * 1024;
  unsigned char* p = (unsigned char*)d_ws;
  auto take = [&](size_t bytes) { void* r = (void*)p; p += bytes; return r; };

  unsigned short* wtq = (unsigned short*)take(W_E * 2);
  unsigned short* wtk = (unsigned short*)take(W_E * 2);
  unsigned short* wtv = (unsigned short*)take(W_E * 2);
  unsigned short* wto = (unsigned short*)take(W_E * 2);
  unsigned short* xq = (unsigned short*)take(X_E * 2);
  unsigned short* xk = (unsigned short*)take(X_E * 2);
  unsigned short* xv = (unsigned short*)take(X_E * 2);
  unsigned short* Qb = (unsigned short*)take(X_E * 2);
  unsigned short* Kb = (unsigned short*)take(X_E * 2);
  unsigned short* Vt = (unsigned short*)take(X_E * 2);
  unsigned short* ao = (unsigned short*)take(X_E * 2);
  (void)ws_size; (void)in_sizes; (void)n_in; (void)out_size;

  transw<<<dim3(256, 4), 256, 0, stream>>>(Wq, wtq, Wk, wtk, Wv, wtv, Wo, wto);
  convert_x3<<<dim3(4096, 3), 256, 0, stream>>>(query, xq, key, xk, value, xv);

  QkvArgs qkv = {};
  qkv.A[0] = xq; qkv.B[0] = wtq; qkv.bias[0] = bq; qkv.out[0] = Qb;
  qkv.A[1] = xk; qkv.B[1] = wtk; qkv.bias[1] = bk; qkv.out[1] = Kb;
  qkv.A[2] = xv; qkv.B[2] = wtv; qkv.bias[2] = bv; qkv.out[2] = Vt;
  gemm_qkv<<<dim3(192), 512, 0, stream>>>(qkv);

  attn_mfma<<<dim3(1024), 256, 0, stream>>>(Qb, Kb, Vt, ao);

  gemm_oproj<<<dim3(256), 256, 0, stream>>>(ao, wto, bo, out);
}

// Round 13
// 76.963 us; speedup vs baseline: 1.1756x; 1.0518x over previous
//
#include <hip/hip_runtime.h>
#include <hip/hip_bf16.h>

// ---------- helpers ----------
typedef __attribute__((ext_vector_type(4))) float f32x4;
typedef __attribute__((ext_vector_type(8))) short s16x8;

#define MFMA16(a, b, c) __builtin_amdgcn_mfma_f32_16x16x32_bf16(a, b, c, 0, 0, 0)

__device__ __forceinline__ void gld_lds16(const void* g, void* l) {
  __builtin_amdgcn_global_load_lds(
      (const __attribute__((address_space(1))) unsigned int*)g,
      (__attribute__((address_space(3))) unsigned int*)l, 16, 0, 0);
}

__device__ __forceinline__ unsigned short f2bf(float f) {
  union { __hip_bfloat16 b; unsigned short u; } cv;
  cv.b = __float2bfloat16(f);
  return cv.u;
}
__device__ __forceinline__ float bf2f(unsigned short u) {
  union { unsigned short u; __hip_bfloat16 b; } cv;
  cv.u = u;
  return __bfloat162float(cv.b);
}

// ---------- kernel 1: merged prepass ----------
// bid < 12288: X f32 -> bf16 convert (3 tensors).
// bid >= 12288: W [K][N] f32 -> W^T [N][K] bf16 (4 weights).
__global__ void prep(const float* Xq, unsigned short* xq,
                     const float* Xk, unsigned short* xk,
                     const float* Xv, unsigned short* xv,
                     const float* W0, unsigned short* H0,
                     const float* W1, unsigned short* H1,
                     const float* W2, unsigned short* H2,
                     const float* W3, unsigned short* H3) {
  __shared__ float tile[64 * 65];
  const int bid = blockIdx.x;
  const int t = threadIdx.x;
  if (bid < 12288) {
    const float* src; unsigned short* h;
    const int which = bid / 4096;
    if (which == 0) { src = Xq; h = xq; }
    else if (which == 1) { src = Xk; h = xk; }
    else { src = Xv; h = xv; }
    const int i = (bid - which * 4096) * 256 + t;   // float4 unit
    float4 v = ((const float4*)src)[i];
    ((ushort4*)h)[i] = make_ushort4(f2bf(v.x), f2bf(v.y), f2bf(v.z), f2bf(v.w));
  } else {
    const int bid2 = bid - 12288;
    const float* W; unsigned short* H;
    switch (bid2 >> 8) {
      case 0: W = W0; H = H0; break;
      case 1: W = W1; H = H1; break;
      case 2: W = W2; H = H2; break;
      default: W = W3; H = H3; break;
    }
    const int tx = bid2 & 255;
    const int tk0 = (tx & 15) * 64;   // k tile
    const int tn0 = (tx >> 4) * 64;   // n tile
    for (int i = 0; i < 16; ++i) {
      int idx = i * 256 + t;
      int r = idx >> 6, c = idx & 63;
      tile[r * 65 + c] = W[(size_t)(tk0 + r) * 1024 + tn0 + c];
    }
    __syncthreads();
    for (int i = 0; i < 16; ++i) {
      int idx = i * 256 + t;
      int r = idx >> 6, c = idx & 63;   // r: n offset, c: k offset
      H[(size_t)(tn0 + r) * 1024 + tk0 + c] = f2bf(tile[c * 65 + r]);
    }
  }
}

// ---------- LDS layout (BK=64, bf16) ----------
// One matrix row = 64 shorts = one 128-B LDS row. Granule gno (8 shorts) of
// row r stored at slot gno^(r&7); gno -> k offset (gno>>2)*32 + (gno&3)*8.
// Read frag (row ar, k-group ks, lane gh): slot = ((ks<<2)|gh) ^ (ar&7).

// ---------- kernel 3a: QKV bf16 GEMM, 256x256 tile, 8 waves, BK=64, dbuf ----------
// R10 schedule (measured best): stage-all(t+1) at step top; one vmcnt(0)+
// barrier per step. Epilogue via LDS transpose; V stored n-major w/ XOR
// (conflict-free b128 readback).
// g==0,1 (Q,K): out [b*16+h][s][64]. g==2 (V): out TRANSPOSED [b*16+h][d][2048 s].
struct QkvArgs {
  const unsigned short* A[3];
  const unsigned short* B[3];
  const float* bias[3];
  unsigned short* out[3];
};

__global__ __launch_bounds__(512, 2)
void gemm_qkv(QkvArgs args) {
  const int K = 1024;
  __shared__ __align__(16) unsigned short lds[65536];   // 128 KB
  const int tid = threadIdx.x;
  const int lane = tid & 63, w = tid >> 6;

  // XCD-aware bijective swizzle (192 % 8 == 0)
  const int nwg = 192;
  const int orig = blockIdx.x;
  const int swz = (orig & 7) * (nwg >> 3) + (orig >> 3);
  const int g = swz >> 6;          // 64 blocks per gemm (16 M x 4 N)
  const int tl = swz & 63;
  const int m0 = (tl >> 2) * 256, n0 = (tl & 3) * 256;

  const unsigned short* A = args.A[g];
  const unsigned short* B = args.B[g];
  const float* bias = args.bias[g];
  unsigned short* out = args.out[g];

  const int wm = (w >> 2) * 128, wn = (w & 3) * 64;   // wave tile 128x64
  const int fr = lane & 15, gh = lane >> 4;

  // staging sources: 4 sweeps per matrix per K-tile (8 gld/thread/step)
  const unsigned short* aP[4]; const unsigned short* bP[4]; int dstoff[4];
  #pragma unroll
  for (int s = 0; s < 4; ++s) {
    const int G = s * 512 + tid;
    const int r = G >> 3, slot = G & 7;
    const int gno = slot ^ (r & 7);
    const int ko = (gno >> 2) * 32 + (gno & 3) * 8;
    aP[s] = A + (size_t)(m0 + r) * K + ko;
    bP[s] = B + (size_t)(n0 + r) * K + ko;
    dstoff[s] = G * 8;
  }
  auto stageAll = [&](int u, int kt) {
    #pragma unroll
    for (int s = 0; s < 4; ++s) {
      gld_lds16(aP[s] + kt, &lds[u * 16384 + dstoff[s]]);
      gld_lds16(bP[s] + kt, &lds[32768 + u * 16384 + dstoff[s]]);
    }
  };

  f32x4 acc[8][4] = {};

  // prologue: stage K-tile 0 into buf 0
  stageAll(0, 0);
  asm volatile("s_waitcnt vmcnt(0)" ::: "memory");
  __builtin_amdgcn_s_barrier();
  __builtin_amdgcn_sched_barrier(0);

  #pragma unroll 1
  for (int t = 0; t < 16; ++t) {
    const int u = t & 1;
    if (t < 15) stageAll(u ^ 1, (t + 1) * 64);   // issue early: full step in flight
    const unsigned short* La = &lds[u * 16384];
    const unsigned short* Lb = &lds[32768 + u * 16384];
    s16x8 b[2][4];
    #pragma unroll
    for (int ks = 0; ks < 2; ++ks)
      #pragma unroll
      for (int nt = 0; nt < 4; ++nt) {
        const int br = wn + nt * 16 + fr;
        b[ks][nt] = *(const s16x8*)&Lb[br * 64 + (((ks << 2) | gh) ^ (br & 7)) * 8];
      }
    #pragma unroll
    for (int q = 0; q < 4; ++q) {
      s16x8 a[2][2];
      #pragma unroll
      for (int i = 0; i < 2; ++i)
        #pragma unroll
        for (int ks = 0; ks < 2; ++ks) {
          const int ar = wm + (q * 2 + i) * 16 + fr;
          a[i][ks] = *(const s16x8*)&La[ar * 64 + (((ks << 2) | gh) ^ (ar & 7)) * 8];
        }
      #pragma unroll
      for (int i = 0; i < 2; ++i)
        #pragma unroll
        for (int nt = 0; nt < 4; ++nt) {
          acc[q * 2 + i][nt] = MFMA16(a[i][0], b[0][nt], acc[q * 2 + i][nt]);
          acc[q * 2 + i][nt] = MFMA16(a[i][1], b[1][nt], acc[q * 2 + i][nt]);
        }
    }
    __builtin_amdgcn_sched_barrier(0);
    if (t < 15) { asm volatile("s_waitcnt vmcnt(0)" ::: "memory"); }
    __builtin_amdgcn_s_barrier();
    __builtin_amdgcn_sched_barrier(0);
  }

  // ---- epilogue: acc -> LDS (256x256 bf16, 128 KB) -> coalesced 16B stores
  float bv[4];
  #pragma unroll
  for (int nt = 0; nt < 4; ++nt) bv[nt] = bias[n0 + wn + nt * 16 + fr];
  unsigned short* eb = &lds[0];   // 65536 shorts = 256 x 256
  __syncthreads();
  if (g == 2) {
    // V: store C^T n-major with per-row XOR; s-major re-read is b128 conflict-free
    #pragma unroll
    for (int mt = 0; mt < 8; ++mt)
      #pragma unroll
      for (int nt = 0; nt < 4; ++nt) {
        const int nl = wn + nt * 16 + fr;
        f32x4 r = acc[mt][nt];
        #pragma unroll
        for (int j = 0; j < 4; ++j) {
          const int sl = wm + mt * 16 + gh * 4 + j;
          eb[nl * 256 + (sl ^ ((nl & 7) << 3))] = f2bf(r[j] + bv[nt]);
        }
      }
  } else {
    #pragma unroll
    for (int mt = 0; mt < 8; ++mt)
      #pragma unroll
      for (int nt = 0; nt < 4; ++nt) {
        const int nl = wn + nt * 16 + fr;
        f32x4 r = acc[mt][nt];
        #pragma unroll
        for (int j = 0; j < 4; ++j) {
          const int sl = wm + mt * 16 + gh * 4 + j;
          eb[sl * 256 + nl] = f2bf(r[j] + bv[nt]);
        }
      }
  }
  __syncthreads();
  const int b2 = m0 >> 11;
  if (g == 2) {
    // out[b*16+h][d][2048 s]: thread copies 8 shorts along s (b128 LDS read)
    #pragma unroll
    for (int it = 0; it < 16; ++it) {
      const int u = it * 512 + tid;
      const int nl = u >> 5, sc = u & 31;
      s16x8 v = *(const s16x8*)&eb[nl * 256 + ((sc * 8) ^ ((nl & 7) << 3))];
      const int gn = n0 + nl, h = gn >> 6, d = gn & 63;
      *(s16x8*)&out[((size_t)((b2 * 16 + h) * 64 + d)) * 2048 + (m0 & 2047) + sc * 8] = v;
    }
  } else {
    // out[b*16+h][s][64]: thread copies 8 shorts along d (16B store)
    #pragma unroll
    for (int it = 0; it < 16; ++it) {
      const int u = it * 512 + tid;
      const int sl = u >> 5, n8 = (u & 31) * 8;
      s16x8 v = *(const s16x8*)&eb[sl * 256 + n8];
      const int s = m0 + sl;
      const int gn = n0 + n8, h = gn >> 6, d = gn & 63;
      *(s16x8*)&out[(((size_t)(b2 * 16 + h)) * 2048 + (s & 2047)) * 64 + d] = v;
    }
  }
}

// ---------- kernel 3b: O-proj bf16 GEMM, 128x128 tile, 4 waves, BK=64, dbuf ----------
__global__ __launch_bounds__(256, 2)
void gemm_oproj(const unsigned short* __restrict__ A, const unsigned short* __restrict__ B,
                const float* __restrict__ bias, float* __restrict__ out) {
  const int K = 1024, N = 1024;
  __shared__ __align__(16) unsigned short lds[32768];   // 64 KB
  const int tid = threadIdx.x;
  const int lane = tid & 63, wid = tid >> 6;

  const int nwg = 256;
  const int orig = blockIdx.x;
  const int swz = (orig & 7) * (nwg >> 3) + (orig >> 3);
  const int m0 = (swz >> 3) * 128, n0 = (swz & 7) * 128;

  const int wm = (wid >> 1) * 64, wn = (wid & 1) * 64;
  const int fr = lane & 15, gh = lane >> 4;

  const unsigned short* aP[4]; const unsigned short* bP[4]; int dstoff[4];
  #pragma unroll
  for (int s = 0; s < 4; ++s) {
    const int G = s * 256 + tid;
    const int r = G >> 3, slot = G & 7;
    const int gno = slot ^ (r & 7);
    const int ko = (gno >> 2) * 32 + (gno & 3) * 8;
    aP[s] = A + (size_t)(m0 + r) * K + ko;
    bP[s] = B + (size_t)(n0 + r) * K + ko;
    dstoff[s] = G * 8;
  }
  auto stageAll = [&](int u, int kt) {
    #pragma unroll
    for (int s = 0; s < 4; ++s) {
      gld_lds16(aP[s] + kt, &lds[u * 8192 + dstoff[s]]);
      gld_lds16(bP[s] + kt, &lds[16384 + u * 8192 + dstoff[s]]);
    }
  };

  f32x4 acc[4][4] = {};

  stageAll(0, 0);
  asm volatile("s_waitcnt vmcnt(0)" ::: "memory");
  __builtin_amdgcn_s_barrier();
  __builtin_amdgcn_sched_barrier(0);

  #pragma unroll 1
  for (int t = 0; t < 16; ++t) {
    const int u = t & 1;
    if (t < 15) stageAll(u ^ 1, (t + 1) * 64);
    const unsigned short* La = &lds[u * 8192];
    const unsigned short* Lb = &lds[16384 + u * 8192];
    s16x8 b[2][4];
    #pragma unroll
    for (int ks = 0; ks < 2; ++ks)
      #pragma unroll
      for (int nt = 0; nt < 4; ++nt) {
        const int br = wn + nt * 16 + fr;
        b[ks][nt] = *(const s16x8*)&Lb[br * 64 + (((ks << 2) | gh) ^ (br & 7)) * 8];
      }
    #pragma unroll
    for (int q = 0; q < 2; ++q) {
      s16x8 a[2][2];
      #pragma unroll
      for (int i = 0; i < 2; ++i)
        #pragma unroll
        for (int ks = 0; ks < 2; ++ks) {
          const int ar = wm + (q * 2 + i) * 16 + fr;
          a[i][ks] = *(const s16x8*)&La[ar * 64 + (((ks << 2) | gh) ^ (ar & 7)) * 8];
        }
      #pragma unroll
      for (int i = 0; i < 2; ++i)
        #pragma unroll
        for (int nt = 0; nt < 4; ++nt) {
          acc[q * 2 + i][nt] = MFMA16(a[i][0], b[0][nt], acc[q * 2 + i][nt]);
          acc[q * 2 + i][nt] = MFMA16(a[i][1], b[1][nt], acc[q * 2 + i][nt]);
        }
    }
    __builtin_amdgcn_sched_barrier(0);
    if (t < 15) { asm volatile("s_waitcnt vmcnt(0)" ::: "memory"); }
    __builtin_amdgcn_s_barrier();
    __builtin_amdgcn_sched_barrier(0);
  }

  #pragma unroll
  for (int mt = 0; mt < 4; ++mt) {
    const int gm = m0 + wm + mt * 16 + (gh << 2);
    #pragma unroll
    for (int nt = 0; nt < 4; ++nt) {
      const int gn = n0 + wn + nt * 16 + fr;
      const float bvv = bias[gn];
      f32x4 r = acc[mt][nt];
      #pragma unroll
      for (int j = 0; j < 4; ++j)
        out[(size_t)(gm + j) * N + gn] = r[j] + bvv;
    }
  }
}

// ---------- kernel 4: block-diagonal attention, MFMA core ----------
// grid 1024 = hb*32 + qb. Q,K: [hb][2048 s][64 d] bf16. Vt: [hb][64 d][2048 s] bf16.
// LDS tiles [64][64] bf16 with granule-XOR. V staged with deferred drain:
// QK^T+softmax run under V's latency (vmcnt(2) gate; raw barriers).
__global__ __launch_bounds__(256, 2)
void attn_mfma(const unsigned short* __restrict__ Q, const unsigned short* __restrict__ Kb,
               const unsigned short* __restrict__ Vt, unsigned short* __restrict__ X) {
  __shared__ __align__(16) unsigned short qs[4096];
  __shared__ __align__(16) unsigned short ks2[4096];
  __shared__ __align__(16) unsigned short vs[4096];
  __shared__ __align__(16) unsigned short ps[4096];
  const int tid = threadIdx.x, lane = tid & 63, w = tid >> 6;
  const int hb = blockIdx.x >> 5, qb = blockIdx.x & 31;
  const size_t qkbase = ((size_t)hb * 2048 + qb * 64) * 64;
  const size_t vbase = (size_t)hb * 64 * 2048 + qb * 64;

  // stage Q,K first, then V (issue order = retirement order for vmcnt)
  #pragma unroll
  for (int i = 0; i < 2; ++i) {
    const int G = i * 256 + tid;
    const int row = G >> 3, slot = G & 7;
    const int sg = slot ^ (row & 7);
    gld_lds16(Q + qkbase + row * 64 + sg * 8, &qs[G * 8]);
    gld_lds16(Kb + qkbase + row * 64 + sg * 8, &ks2[G * 8]);
  }
  #pragma unroll
  for (int i = 0; i < 2; ++i) {
    const int G = i * 256 + tid;
    const int row = G >> 3, slot = G & 7;
    const int sg = slot ^ (row & 7);
    gld_lds16(Vt + vbase + (size_t)row * 2048 + sg * 8, &vs[G * 8]);
  }
  asm volatile("s_waitcnt vmcnt(2)" ::: "memory");   // Q,K retired; V in flight
  __builtin_amdgcn_s_barrier();
  __builtin_amdgcn_sched_barrier(0);

  const int fr = lane & 15, gh = lane >> 4;
  const int arow = w * 16 + fr;   // this wave's A rows (q)

  // ---- QK^T: S[16q][64k] per wave
  s16x8 aq[2], bk[2][4];
  #pragma unroll
  for (int ks = 0; ks < 2; ++ks) {
    aq[ks] = *(const s16x8*)&qs[arow * 64 + (((ks * 4 + gh) ^ (arow & 7)) << 3)];
    #pragma unroll
    for (int nt = 0; nt < 4; ++nt) {
      const int krow = nt * 16 + fr;
      bk[ks][nt] = *(const s16x8*)&ks2[krow * 64 + (((ks * 4 + gh) ^ (krow & 7)) << 3)];
    }
  }
  f32x4 s[4] = {};
  #pragma unroll
  for (int ks = 0; ks < 2; ++ks)
    #pragma unroll
    for (int nt = 0; nt < 4; ++nt)
      s[nt] = MFMA16(aq[ks], bk[ks][nt], s[nt]);

  // ---- softmax: D row q = gh*4+j, col k = nt*16+fr -> reduce over fr's 16 lanes
  #pragma unroll
  for (int j = 0; j < 4; ++j) {
    float t0 = s[0][j] * 0.125f, t1 = s[1][j] * 0.125f;
    float t2 = s[2][j] * 0.125f, t3 = s[3][j] * 0.125f;
    float m = fmaxf(fmaxf(t0, t1), fmaxf(t2, t3));
    m = fmaxf(m, __shfl_xor(m, 1, 64));
    m = fmaxf(m, __shfl_xor(m, 2, 64));
    m = fmaxf(m, __shfl_xor(m, 4, 64));
    m = fmaxf(m, __shfl_xor(m, 8, 64));
    t0 = __expf(t0 - m); t1 = __expf(t1 - m);
    t2 = __expf(t2 - m); t3 = __expf(t3 - m);
    float sum = t0 + t1 + t2 + t3;
    sum += __shfl_xor(sum, 1, 64);
    sum += __shfl_xor(sum, 2, 64);
    sum += __shfl_xor(sum, 4, 64);
    sum += __shfl_xor(sum, 8, 64);
    const float r = 1.0f / sum;
    s[0][j] = t0 * r; s[1][j] = t1 * r; s[2][j] = t2 * r; s[3][j] = t3 * r;
  }

  // ---- P -> bf16 LDS (swizzled); wave writes/reads only its own 16 rows
  #pragma unroll
  for (int j = 0; j < 4; ++j) {
    const int q = w * 16 + gh * 4 + j;
    #pragma unroll
    for (int nt = 0; nt < 4; ++nt) {
      const int k = nt * 16 + fr;
      ps[q * 64 + (((k >> 3) ^ (q & 7)) << 3) + (k & 7)] = f2bf(s[nt][j]);
    }
  }

  // ---- drain V, sync, then PV
  asm volatile("s_waitcnt vmcnt(0)" ::: "memory");
  __builtin_amdgcn_s_barrier();
  __builtin_amdgcn_sched_barrier(0);

  s16x8 ap[2], bv2[2][4];
  #pragma unroll
  for (int ks = 0; ks < 2; ++ks) {
    ap[ks] = *(const s16x8*)&ps[arow * 64 + (((ks * 4 + gh) ^ (arow & 7)) << 3)];
    #pragma unroll
    for (int nt = 0; nt < 4; ++nt) {
      const int drow = nt * 16 + fr;
      bv2[ks][nt] = *(const s16x8*)&vs[drow * 64 + (((ks * 4 + gh) ^ (drow & 7)) << 3)];
    }
  }
  f32x4 x[4] = {};
  #pragma unroll
  for (int ks = 0; ks < 2; ++ks)
    #pragma unroll
    for (int nt = 0; nt < 4; ++nt)
      x[nt] = MFMA16(ap[ks], bv2[ks][nt], x[nt]);

  // ---- write X: [b*2048 + s][h*64 + d] bf16
  const int b = hb >> 4, h = hb & 15;
  #pragma unroll
  for (int nt = 0; nt < 4; ++nt)
    #pragma unroll
    for (int j = 0; j < 4; ++j) {
      const int sgl = qb * 64 + w * 16 + gh * 4 + j;
      X[((size_t)(b * 2048 + sgl)) * 1024 + h * 64 + nt * 16 + fr] = f2bf(x[nt][j]);
    }
}

// ---------- launch ----------
extern "C" void kernel_launch(void* const* d_in, const int* in_sizes, int n_in,
                              void* d_out, int out_size, void* d_ws, size_t ws_size,
                              hipStream_t stream) {
  const float* query = (const float*)d_in[0];
  const float* key   = (const float*)d_in[1];
  const float* value = (const float*)d_in[2];
  const float* Wq = (const float*)d_in[3]; const float* bq = (const float*)d_in[4];
  const float* Wk = (const float*)d_in[5]; const float* bk = (const float*)d_in[6];
  const float* Wv = (const float*)d_in[7]; const float* bv = (const float*)d_in[8];
  const float* Wo = (const float*)d_in[9]; const float* bo = (const float*)d_in[10];
  float* out = (float*)d_out;

  const size_t W_E = 1024 * 1024;
  const size_t X_E = 4096 * 1024;
  unsigned char* p = (unsigned char*)d_ws;
  auto take = [&](size_t bytes) { void* r = (void*)p; p += bytes; return r; };

  unsigned short* wtq = (unsigned short*)take(W_E * 2);
  unsigned short* wtk = (unsigned short*)take(W_E * 2);
  unsigned short* wtv = (unsigned short*)take(W_E * 2);
  unsigned short* wto = (unsigned short*)take(W_E * 2);
  unsigned short* xq = (unsigned short*)take(X_E * 2);
  unsigned short* xk = (unsigned short*)take(X_E * 2);
  unsigned short* xv = (unsigned short*)take(X_E * 2);
  unsigned short* Qb = (unsigned short*)take(X_E * 2);
  unsigned short* Kb = (unsigned short*)take(X_E * 2);
  unsigned short* Vt = (unsigned short*)take(X_E * 2);
  unsigned short* ao = (unsigned short*)take(X_E * 2);
  (void)ws_size; (void)in_sizes; (void)n_in; (void)out_size;

  // merged convert + transpose prepass
  prep<<<dim3(13312), 256, 0, stream>>>(query, xq, key, xk, value, xv,
                                        Wq, wtq, Wk, wtk, Wv, wtv, Wo, wto);

  QkvArgs qkv = {};
  qkv.A[0] = xq; qkv.B[0] = wtq; qkv.bias[0] = bq; qkv.out[0] = Qb;
  qkv.A[1] = xk; qkv.B[1] = wtk; qkv.bias[1] = bk; qkv.out[1] = Kb;
  qkv.A[2] = xv; qkv.B[2] = wtv; qkv.bias[2] = bv; qkv.out[2] = Vt;
  gemm_qkv<<<dim3(192), 512, 0, stream>>>(qkv);

  attn_mfma<<<dim3(1024), 256, 0, stream>>>(Qb, Kb, Vt, ao);

  gemm_oproj<<<dim3(256), 256, 0, stream>>>(ao, wto, bo, out);
}

// Round 14
// 75.452 us; speedup vs baseline: 1.1992x; 1.0200x over previous
//
#include <hip/hip_runtime.h>
#include <hip/hip_bf16.h>

// ---------- helpers ----------
typedef __attribute__((ext_vector_type(4))) float f32x4;
typedef __attribute__((ext_vector_type(8))) short s16x8;

#define MFMA16(a, b, c) __builtin_amdgcn_mfma_f32_16x16x32_bf16(a, b, c, 0, 0, 0)

__device__ __forceinline__ void gld_lds16(const void* g, void* l) {
  __builtin_amdgcn_global_load_lds(
      (const __attribute__((address_space(1))) unsigned int*)g,
      (__attribute__((address_space(3))) unsigned int*)l, 16, 0, 0);
}

__device__ __forceinline__ unsigned short f2bf(float f) {
  union { __hip_bfloat16 b; unsigned short u; } cv;
  cv.b = __float2bfloat16(f);
  return cv.u;
}
__device__ __forceinline__ float bf2f(unsigned short u) {
  union { unsigned short u; __hip_bfloat16 b; } cv;
  cv.u = u;
  return __bfloat162float(cv.b);
}

// ---------- kernel 1: merged prepass ----------
// bid < 12288: X f32 -> bf16 convert (3 tensors).
// bid >= 12288: W [K][N] f32 -> W^T [N][K] bf16 (4 weights).
__global__ void prep(const float* Xq, unsigned short* xq,
                     const float* Xk, unsigned short* xk,
                     const float* Xv, unsigned short* xv,
                     const float* W0, unsigned short* H0,
                     const float* W1, unsigned short* H1,
                     const float* W2, unsigned short* H2,
                     const float* W3, unsigned short* H3) {
  __shared__ float tile[64 * 65];
  const int bid = blockIdx.x;
  const int t = threadIdx.x;
  if (bid < 12288) {
    const float* src; unsigned short* h;
    const int which = bid / 4096;
    if (which == 0) { src = Xq; h = xq; }
    else if (which == 1) { src = Xk; h = xk; }
    else { src = Xv; h = xv; }
    const int i = (bid - which * 4096) * 256 + t;   // float4 unit
    float4 v = ((const float4*)src)[i];
    ((ushort4*)h)[i] = make_ushort4(f2bf(v.x), f2bf(v.y), f2bf(v.z), f2bf(v.w));
  } else {
    const int bid2 = bid - 12288;
    const float* W; unsigned short* H;
    switch (bid2 >> 8) {
      case 0: W = W0; H = H0; break;
      case 1: W = W1; H = H1; break;
      case 2: W = W2; H = H2; break;
      default: W = W3; H = H3; break;
    }
    const int tx = bid2 & 255;
    const int tk0 = (tx & 15) * 64;   // k tile
    const int tn0 = (tx >> 4) * 64;   // n tile
    for (int i = 0; i < 16; ++i) {
      int idx = i * 256 + t;
      int r = idx >> 6, c = idx & 63;
      tile[r * 65 + c] = W[(size_t)(tk0 + r) * 1024 + tn0 + c];
    }
    __syncthreads();
    for (int i = 0; i < 16; ++i) {
      int idx = i * 256 + t;
      int r = idx >> 6, c = idx & 63;   // r: n offset, c: k offset
      H[(size_t)(tn0 + r) * 1024 + tk0 + c] = f2bf(tile[c * 65 + r]);
    }
  }
}

// ---------- LDS layout (BK=64, bf16) ----------
// One matrix row = 64 shorts = one 128-B LDS row. Granule gno (8 shorts) of
// row r stored at slot gno^(r&7); gno -> k offset (gno>>2)*32 + (gno&3)*8.
// Read frag (row ar, k-group ks, lane gh): slot = ((ks<<2)|gh) ^ (ar&7).

// ---------- kernel 3a: QKV bf16 GEMM, 256x256 tile, 8 waves, BK=64, dbuf ----------
// R10 schedule (measured best): stage-all(t+1) at step top; one vmcnt(0)+
// barrier per step. Epilogue via LDS transpose; V stored n-major w/ XOR.
// g==0,1 (Q,K): out [b*16+h][s][64]. g==2 (V): out TRANSPOSED [b*16+h][d][2048 s].
struct QkvArgs {
  const unsigned short* A[3];
  const unsigned short* B[3];
  const float* bias[3];
  unsigned short* out[3];
};

__global__ __launch_bounds__(512, 2)
void gemm_qkv(QkvArgs args) {
  const int K = 1024;
  __shared__ __align__(16) unsigned short lds[65536];   // 128 KB
  const int tid = threadIdx.x;
  const int lane = tid & 63, w = tid >> 6;

  // XCD-aware bijective swizzle (192 % 8 == 0)
  const int nwg = 192;
  const int orig = blockIdx.x;
  const int swz = (orig & 7) * (nwg >> 3) + (orig >> 3);
  const int g = swz >> 6;          // 64 blocks per gemm (16 M x 4 N)
  const int tl = swz & 63;
  const int m0 = (tl >> 2) * 256, n0 = (tl & 3) * 256;

  const unsigned short* A = args.A[g];
  const unsigned short* B = args.B[g];
  const float* bias = args.bias[g];
  unsigned short* out = args.out[g];

  const int wm = (w >> 2) * 128, wn = (w & 3) * 64;   // wave tile 128x64
  const int fr = lane & 15, gh = lane >> 4;

  // staging sources: 4 sweeps per matrix per K-tile (8 gld/thread/step)
  const unsigned short* aP[4]; const unsigned short* bP[4]; int dstoff[4];
  #pragma unroll
  for (int s = 0; s < 4; ++s) {
    const int G = s * 512 + tid;
    const int r = G >> 3, slot = G & 7;
    const int gno = slot ^ (r & 7);
    const int ko = (gno >> 2) * 32 + (gno & 3) * 8;
    aP[s] = A + (size_t)(m0 + r) * K + ko;
    bP[s] = B + (size_t)(n0 + r) * K + ko;
    dstoff[s] = G * 8;
  }
  auto stageAll = [&](int u, int kt) {
    #pragma unroll
    for (int s = 0; s < 4; ++s) {
      gld_lds16(aP[s] + kt, &lds[u * 16384 + dstoff[s]]);
      gld_lds16(bP[s] + kt, &lds[32768 + u * 16384 + dstoff[s]]);
    }
  };

  f32x4 acc[8][4] = {};

  // prologue: stage K-tile 0 into buf 0
  stageAll(0, 0);
  asm volatile("s_waitcnt vmcnt(0)" ::: "memory");
  __builtin_amdgcn_s_barrier();
  __builtin_amdgcn_sched_barrier(0);

  #pragma unroll 1
  for (int t = 0; t < 16; ++t) {
    const int u = t & 1;
    if (t < 15) stageAll(u ^ 1, (t + 1) * 64);   // issue early: full step in flight
    const unsigned short* La = &lds[u * 16384];
    const unsigned short* Lb = &lds[32768 + u * 16384];
    s16x8 b[2][4];
    #pragma unroll
    for (int ks = 0; ks < 2; ++ks)
      #pragma unroll
      for (int nt = 0; nt < 4; ++nt) {
        const int br = wn + nt * 16 + fr;
        b[ks][nt] = *(const s16x8*)&Lb[br * 64 + (((ks << 2) | gh) ^ (br & 7)) * 8];
      }
    #pragma unroll
    for (int q = 0; q < 4; ++q) {
      s16x8 a[2][2];
      #pragma unroll
      for (int i = 0; i < 2; ++i)
        #pragma unroll
        for (int ks = 0; ks < 2; ++ks) {
          const int ar = wm + (q * 2 + i) * 16 + fr;
          a[i][ks] = *(const s16x8*)&La[ar * 64 + (((ks << 2) | gh) ^ (ar & 7)) * 8];
        }
      #pragma unroll
      for (int i = 0; i < 2; ++i)
        #pragma unroll
        for (int nt = 0; nt < 4; ++nt) {
          acc[q * 2 + i][nt] = MFMA16(a[i][0], b[0][nt], acc[q * 2 + i][nt]);
          acc[q * 2 + i][nt] = MFMA16(a[i][1], b[1][nt], acc[q * 2 + i][nt]);
        }
    }
    __builtin_amdgcn_sched_barrier(0);
    if (t < 15) { asm volatile("s_waitcnt vmcnt(0)" ::: "memory"); }
    __builtin_amdgcn_s_barrier();
    __builtin_amdgcn_sched_barrier(0);
  }

  // ---- epilogue: acc -> LDS (256x256 bf16, 128 KB) -> coalesced 16B stores
  float bv[4];
  #pragma unroll
  for (int nt = 0; nt < 4; ++nt) bv[nt] = bias[n0 + wn + nt * 16 + fr];
  unsigned short* eb = &lds[0];   // 65536 shorts = 256 x 256
  __syncthreads();
  if (g == 2) {
    // V: store C^T n-major with per-row XOR; s-major re-read is b128 conflict-free
    #pragma unroll
    for (int mt = 0; mt < 8; ++mt)
      #pragma unroll
      for (int nt = 0; nt < 4; ++nt) {
        const int nl = wn + nt * 16 + fr;
        f32x4 r = acc[mt][nt];
        #pragma unroll
        for (int j = 0; j < 4; ++j) {
          const int sl = wm + mt * 16 + gh * 4 + j;
          eb[nl * 256 + (sl ^ ((nl & 7) << 3))] = f2bf(r[j] + bv[nt]);
        }
      }
  } else {
    #pragma unroll
    for (int mt = 0; mt < 8; ++mt)
      #pragma unroll
      for (int nt = 0; nt < 4; ++nt) {
        const int nl = wn + nt * 16 + fr;
        f32x4 r = acc[mt][nt];
        #pragma unroll
        for (int j = 0; j < 4; ++j) {
          const int sl = wm + mt * 16 + gh * 4 + j;
          eb[sl * 256 + nl] = f2bf(r[j] + bv[nt]);
        }
      }
  }
  __syncthreads();
  const int b2 = m0 >> 11;
  if (g == 2) {
    // out[b*16+h][d][2048 s]: thread copies 8 shorts along s (b128 LDS read)
    #pragma unroll
    for (int it = 0; it < 16; ++it) {
      const int u = it * 512 + tid;
      const int nl = u >> 5, sc = u & 31;
      s16x8 v = *(const s16x8*)&eb[nl * 256 + ((sc * 8) ^ ((nl & 7) << 3))];
      const int gn = n0 + nl, h = gn >> 6, d = gn & 63;
      *(s16x8*)&out[((size_t)((b2 * 16 + h) * 64 + d)) * 2048 + (m0 & 2047) + sc * 8] = v;
    }
  } else {
    // out[b*16+h][s][64]: thread copies 8 shorts along d (16B store)
    #pragma unroll
    for (int it = 0; it < 16; ++it) {
      const int u = it * 512 + tid;
      const int sl = u >> 5, n8 = (u & 31) * 8;
      s16x8 v = *(const s16x8*)&eb[sl * 256 + n8];
      const int s = m0 + sl;
      const int gn = n0 + n8, h = gn >> 6, d = gn & 63;
      *(s16x8*)&out[(((size_t)(b2 * 16 + h)) * 2048 + (s & 2047)) * 64 + d] = v;
    }
  }
}

// ---------- kernel 3b: O-proj bf16 GEMM, 128x64 tile, 4 waves, BK=64, dbuf ----------
// 512 blocks, 48 KB LDS -> 3 blocks/CU capacity (~2 resident): cross-block
// overlap fills the per-step barrier drain (mechanism: m114/R2 evidence).
__global__ __launch_bounds__(256, 3)
void gemm_oproj(const unsigned short* __restrict__ A, const unsigned short* __restrict__ B,
                const float* __restrict__ bias, float* __restrict__ out) {
  const int K = 1024, N = 1024;
  __shared__ __align__(16) unsigned short lds[24576];   // A 2x16KB | B 2x8KB = 48 KB
  const int tid = threadIdx.x;
  const int lane = tid & 63, wid = tid >> 6;

  // XCD-aware bijective swizzle (512 % 8 == 0)
  const int nwg = 512;
  const int orig = blockIdx.x;
  const int swz = (orig & 7) * (nwg >> 3) + (orig >> 3);
  const int m0 = (swz >> 4) * 128, n0 = (swz & 15) * 64;

  const int wm = (wid >> 1) * 64, wn = (wid & 1) * 32;   // wave tile 64x32
  const int fr = lane & 15, gh = lane >> 4;

  // A: 128 rows -> 4 sweeps; B: 64 rows -> 2 sweeps
  const unsigned short* aP[4]; int aDst[4];
  #pragma unroll
  for (int s = 0; s < 4; ++s) {
    const int G = s * 256 + tid;
    const int r = G >> 3, slot = G & 7;
    const int gno = slot ^ (r & 7);
    const int ko = (gno >> 2) * 32 + (gno & 3) * 8;
    aP[s] = A + (size_t)(m0 + r) * K + ko;
    aDst[s] = G * 8;
  }
  const unsigned short* bP[2]; int bDst[2];
  #pragma unroll
  for (int s = 0; s < 2; ++s) {
    const int G = s * 256 + tid;
    const int r = G >> 3, slot = G & 7;
    const int gno = slot ^ (r & 7);
    const int ko = (gno >> 2) * 32 + (gno & 3) * 8;
    bP[s] = B + (size_t)(n0 + r) * K + ko;
    bDst[s] = G * 8;
  }
  auto stageAll = [&](int u, int kt) {
    #pragma unroll
    for (int s = 0; s < 4; ++s)
      gld_lds16(aP[s] + kt, &lds[u * 8192 + aDst[s]]);
    #pragma unroll
    for (int s = 0; s < 2; ++s)
      gld_lds16(bP[s] + kt, &lds[16384 + u * 4096 + bDst[s]]);
  };

  f32x4 acc[4][2] = {};

  stageAll(0, 0);
  asm volatile("s_waitcnt vmcnt(0)" ::: "memory");
  __builtin_amdgcn_s_barrier();
  __builtin_amdgcn_sched_barrier(0);

  #pragma unroll 1
  for (int t = 0; t < 16; ++t) {
    const int u = t & 1;
    if (t < 15) stageAll(u ^ 1, (t + 1) * 64);
    const unsigned short* La = &lds[u * 8192];
    const unsigned short* Lb = &lds[16384 + u * 4096];
    s16x8 b[2][2];
    #pragma unroll
    for (int ks = 0; ks < 2; ++ks)
      #pragma unroll
      for (int nt = 0; nt < 2; ++nt) {
        const int br = wn + nt * 16 + fr;
        b[ks][nt] = *(const s16x8*)&Lb[br * 64 + (((ks << 2) | gh) ^ (br & 7)) * 8];
      }
    #pragma unroll
    for (int q = 0; q < 2; ++q) {
      s16x8 a[2][2];
      #pragma unroll
      for (int i = 0; i < 2; ++i)
        #pragma unroll
        for (int ks = 0; ks < 2; ++ks) {
          const int ar = wm + (q * 2 + i) * 16 + fr;
          a[i][ks] = *(const s16x8*)&La[ar * 64 + (((ks << 2) | gh) ^ (ar & 7)) * 8];
        }
      #pragma unroll
      for (int i = 0; i < 2; ++i)
        #pragma unroll
        for (int nt = 0; nt < 2; ++nt) {
          acc[q * 2 + i][nt] = MFMA16(a[i][0], b[0][nt], acc[q * 2 + i][nt]);
          acc[q * 2 + i][nt] = MFMA16(a[i][1], b[1][nt], acc[q * 2 + i][nt]);
        }
    }
    __builtin_amdgcn_sched_barrier(0);
    if (t < 15) { asm volatile("s_waitcnt vmcnt(0)" ::: "memory"); }
    __builtin_amdgcn_s_barrier();
    __builtin_amdgcn_sched_barrier(0);
  }

  #pragma unroll
  for (int mt = 0; mt < 4; ++mt) {
    const int gm = m0 + wm + mt * 16 + (gh << 2);
    #pragma unroll
    for (int nt = 0; nt < 2; ++nt) {
      const int gn = n0 + wn + nt * 16 + fr;
      const float bvv = bias[gn];
      f32x4 r = acc[mt][nt];
      #pragma unroll
      for (int j = 0; j < 4; ++j)
        out[(size_t)(gm + j) * N + gn] = r[j] + bvv;
    }
  }
}

// ---------- kernel 4: block-diagonal attention, MFMA core ----------
// grid 1024 = hb*32 + qb. Q,K: [hb][2048 s][64 d] bf16. Vt: [hb][64 d][2048 s] bf16.
// 32 KB LDS, __launch_bounds__(256,4): 4 co-resident blocks/CU hide fetch latency.
__global__ __launch_bounds__(256, 4)
void attn_mfma(const unsigned short* __restrict__ Q, const unsigned short* __restrict__ Kb,
               const unsigned short* __restrict__ Vt, unsigned short* __restrict__ X) {
  __shared__ __align__(16) unsigned short qs[4096];
  __shared__ __align__(16) unsigned short ks2[4096];
  __shared__ __align__(16) unsigned short vs[4096];
  __shared__ __align__(16) unsigned short ps[4096];
  const int tid = threadIdx.x, lane = tid & 63, w = tid >> 6;
  const int hb = blockIdx.x >> 5, qb = blockIdx.x & 31;
  const size_t qkbase = ((size_t)hb * 2048 + qb * 64) * 64;
  const size_t vbase = (size_t)hb * 64 * 2048 + qb * 64;

  // stage Q,K first, then V (issue order = retirement order for vmcnt)
  #pragma unroll
  for (int i = 0; i < 2; ++i) {
    const int G = i * 256 + tid;
    const int row = G >> 3, slot = G & 7;
    const int sg = slot ^ (row & 7);
    gld_lds16(Q + qkbase + row * 64 + sg * 8, &qs[G * 8]);
    gld_lds16(Kb + qkbase + row * 64 + sg * 8, &ks2[G * 8]);
  }
  #pragma unroll
  for (int i = 0; i < 2; ++i) {
    const int G = i * 256 + tid;
    const int row = G >> 3, slot = G & 7;
    const int sg = slot ^ (row & 7);
    gld_lds16(Vt + vbase + (size_t)row * 2048 + sg * 8, &vs[G * 8]);
  }
  asm volatile("s_waitcnt vmcnt(2)" ::: "memory");   // Q,K retired; V in flight
  __builtin_amdgcn_s_barrier();
  __builtin_amdgcn_sched_barrier(0);

  const int fr = lane & 15, gh = lane >> 4;
  const int arow = w * 16 + fr;   // this wave's A rows (q)

  // ---- QK^T: S[16q][64k] per wave
  s16x8 aq[2], bk[2][4];
  #pragma unroll
  for (int ks = 0; ks < 2; ++ks) {
    aq[ks] = *(const s16x8*)&qs[arow * 64 + (((ks * 4 + gh) ^ (arow & 7)) << 3)];
    #pragma unroll
    for (int nt = 0; nt < 4; ++nt) {
      const int krow = nt * 16 + fr;
      bk[ks][nt] = *(const s16x8*)&ks2[krow * 64 + (((ks * 4 + gh) ^ (krow & 7)) << 3)];
    }
  }
  f32x4 s[4] = {};
  #pragma unroll
  for (int ks = 0; ks < 2; ++ks)
    #pragma unroll
    for (int nt = 0; nt < 4; ++nt)
      s[nt] = MFMA16(aq[ks], bk[ks][nt], s[nt]);

  // ---- softmax: D row q = gh*4+j, col k = nt*16+fr -> reduce over fr's 16 lanes
  #pragma unroll
  for (int j = 0; j < 4; ++j) {
    float t0 = s[0][j] * 0.125f, t1 = s[1][j] * 0.125f;
    float t2 = s[2][j] * 0.125f, t3 = s[3][j] * 0.125f;
    float m = fmaxf(fmaxf(t0, t1), fmaxf(t2, t3));
    m = fmaxf(m, __shfl_xor(m, 1, 64));
    m = fmaxf(m, __shfl_xor(m, 2, 64));
    m = fmaxf(m, __shfl_xor(m, 4, 64));
    m = fmaxf(m, __shfl_xor(m, 8, 64));
    t0 = __expf(t0 - m); t1 = __expf(t1 - m);
    t2 = __expf(t2 - m); t3 = __expf(t3 - m);
    float sum = t0 + t1 + t2 + t3;
    sum += __shfl_xor(sum, 1, 64);
    sum += __shfl_xor(sum, 2, 64);
    sum += __shfl_xor(sum, 4, 64);
    sum += __shfl_xor(sum, 8, 64);
    const float r = 1.0f / sum;
    s[0][j] = t0 * r; s[1][j] = t1 * r; s[2][j] = t2 * r; s[3][j] = t3 * r;
  }

  // ---- P -> bf16 LDS (swizzled); wave writes/reads only its own 16 rows
  #pragma unroll
  for (int j = 0; j < 4; ++j) {
    const int q = w * 16 + gh * 4 + j;
    #pragma unroll
    for (int nt = 0; nt < 4; ++nt) {
      const int k = nt * 16 + fr;
      ps[q * 64 + (((k >> 3) ^ (q & 7)) << 3) + (k & 7)] = f2bf(s[nt][j]);
    }
  }

  // ---- drain V, sync, then PV
  asm volatile("s_waitcnt vmcnt(0)" ::: "memory");
  __builtin_amdgcn_s_barrier();
  __builtin_amdgcn_sched_barrier(0);

  s16x8 ap[2], bv2[2][4];
  #pragma unroll
  for (int ks = 0; ks < 2; ++ks) {
    ap[ks] = *(const s16x8*)&ps[arow * 64 + (((ks * 4 + gh) ^ (arow & 7)) << 3)];
    #pragma unroll
    for (int nt = 0; nt < 4; ++nt) {
      const int drow = nt * 16 + fr;
      bv2[ks][nt] = *(const s16x8*)&vs[drow * 64 + (((ks * 4 + gh) ^ (drow & 7)) << 3)];
    }
  }
  f32x4 x[4] = {};
  #pragma unroll
  for (int ks = 0; ks < 2; ++ks)
    #pragma unroll
    for (int nt = 0; nt < 4; ++nt)
      x[nt] = MFMA16(ap[ks], bv2[ks][nt], x[nt]);

  // ---- write X: [b*2048 + s][h*64 + d] bf16
  const int b = hb >> 4, h = hb & 15;
  #pragma unroll
  for (int nt = 0; nt < 4; ++nt)
    #pragma unroll
    for (int j = 0; j < 4; ++j) {
      const int sgl = qb * 64 + w * 16 + gh * 4 + j;
      X[((size_t)(b * 2048 + sgl)) * 1024 + h * 64 + nt * 16 + fr] = f2bf(x[nt][j]);
    }
}

// ---------- launch ----------
extern "C" void kernel_launch(void* const* d_in, const int* in_sizes, int n_in,
                              void* d_out, int out_size, void* d_ws, size_t ws_size,
                              hipStream_t stream) {
  const float* query = (const float*)d_in[0];
  const float* key   = (const float*)d_in[1];
  const float* value = (const float*)d_in[2];
  const float* Wq = (const float*)d_in[3]; const float* bq = (const float*)d_in[4];
  const float* Wk = (const float*)d_in[5]; const float* bk = (const float*)d_in[6];
  const float* Wv = (const float*)d_in[7]; const float* bv = (const float*)d_in[8];
  const float* Wo = (const float*)d_in[9]; const float* bo = (const float*)d_in[10];
  float* out = (float*)d_out;

  const size_t W_E = 1024 * 1024;
  const size_t X_E = 4096 * 1024;
  unsigned char* p = (unsigned char*)d_ws;
  auto take = [&](size_t bytes) { void* r = (void*)p; p += bytes; return r; };

  unsigned short* wtq = (unsigned short*)take(W_E * 2);
  unsigned short* wtk = (unsigned short*)take(W_E * 2);
  unsigned short* wtv = (unsigned short*)take(W_E * 2);
  unsigned short* wto = (unsigned short*)take(W_E * 2);
  unsigned short* xq = (unsigned short*)take(X_E * 2);
  unsigned short* xk = (unsigned short*)take(X_E * 2);
  unsigned short* xv = (unsigned short*)take(X_E * 2);
  unsigned short* Qb = (unsigned short*)take(X_E * 2);
  unsigned short* Kb = (unsigned short*)take(X_E * 2);
  unsigned short* Vt = (unsigned short*)take(X_E * 2);
  unsigned short* ao = (unsigned short*)take(X_E * 2);
  (void)ws_size; (void)in_sizes; (void)n_in; (void)out_size;

  // merged convert + transpose prepass
  prep<<<dim3(13312), 256, 0, stream>>>(query, xq, key, xk, value, xv,
                                        Wq, wtq, Wk, wtk, Wv, wtv, Wo, wto);

  QkvArgs qkv = {};
  qkv.A[0] = xq; qkv.B[0] = wtq; qkv.bias[0] = bq; qkv.out[0] = Qb;
  qkv.A[1] = xk; qkv.B[1] = wtk; qkv.bias[1] = bk; qkv.out[1] = Kb;
  qkv.A[2] = xv; qkv.B[2] = wtv; qkv.bias[2] = bv; qkv.out[2] = Vt;
  gemm_qkv<<<dim3(192), 512, 0, stream>>>(qkv);

  attn_mfma<<<dim3(1024), 256, 0, stream>>>(Qb, Kb, Vt, ao);

  gemm_oproj<<<dim3(512), 256, 0, stream>>>(ao, wto, bo, out);
}